// Round 2
// baseline (2232.190 us; speedup 1.0000x reference)
//
#include <hip/hip_runtime.h>
#include <hip/hip_bf16.h>
#include <math.h>

#define NND 20000
#define NED 320000
#define NB 4
#define NFEAT 8
#define ADF 8
#define DD 128
#define NEGINF -1000000000.0f

__device__ __forceinline__ unsigned ftrans(float f) {
    unsigned u = __float_as_uint(f);
    return (u & 0x80000000u) ? ~u : (u | 0x80000000u);
}
__device__ __forceinline__ float finv(unsigned t) {
    unsigned u = (t & 0x80000000u) ? (t & 0x7fffffffu) : ~t;
    return __uint_as_float(u);
}

// ---------------- init scratch accumulators ----------------
__global__ void k_init(float* stats, int* deg, unsigned* mtrans, float* S, float* ctx, float* raw) {
    int i = blockIdx.x * 256 + threadIdx.x;
    if (i < 16) stats[i] = 0.f;
    if (i < NB * NND) { deg[i] = 0; raw[i] = 0.f; }
    if (i < NB) { mtrans[i] = 0u; S[i] = 0.f; }
    if (i < NB * DD) ctx[i] = 0.f;
}

// ---------------- mask dtype detection (bool/uint8 vs int32) ----------------
// For int32 0/1 values, every byte at offset p with p%4!=0 is zero.
// For uint8 random 0/1, some byte among the first 4096 at p%4!=0 is 1 (P_fail ~ 2^-3000).
__global__ void k_flag(const unsigned char* __restrict__ m, int* flag) {
    __shared__ int any;
    if (threadIdx.x == 0) any = 0;
    __syncthreads();
    int found = 0;
    for (int p = threadIdx.x; p < 4096; p += 256)
        if ((p & 3) && m[p]) found = 1;
    if (found) atomicOr(&any, 1);
    __syncthreads();
    if (threadIdx.x == 0) *flag = any;
}

__global__ void k_maskc(const void* __restrict__ m, const int* __restrict__ flag, int* __restrict__ mc) {
    int g = blockIdx.x * 256 + threadIdx.x;
    if (g >= NB * NND) return;
    int f = *flag;
    mc[g] = f ? (int)((const unsigned char*)m)[g] : ((const int*)m)[g];
}

// ---------------- node feature mean/var sums ----------------
__global__ __launch_bounds__(256) void k_stats(const float* __restrict__ nodes, float* stats) {
    int tid = threadIdx.x;
    int gid = blockIdx.x * 256 + tid;
    float s[8] = {0.f,0.f,0.f,0.f,0.f,0.f,0.f,0.f};
    float q[8] = {0.f,0.f,0.f,0.f,0.f,0.f,0.f,0.f};
    for (int r = gid; r < NB * NND; r += 256 * 256) {
        const float* p = nodes + (size_t)r * NFEAT;
#pragma unroll
        for (int k = 0; k < 8; ++k) { float v = p[k]; s[k] += v; q[k] += v * v; }
    }
#pragma unroll
    for (int k = 0; k < 8; ++k) {
        for (int off = 32; off; off >>= 1) {
            s[k] += __shfl_xor(s[k], off, 64);
            q[k] += __shfl_xor(q[k], off, 64);
        }
    }
    __shared__ float ls[4][16];
    int w = tid >> 6, lane = tid & 63;
    if (lane == 0) {
#pragma unroll
        for (int k = 0; k < 8; ++k) { ls[w][k] = s[k]; ls[w][8 + k] = q[k]; }
    }
    __syncthreads();
    if (tid < 16) {
        float t = ls[0][tid] + ls[1][tid] + ls[2][tid] + ls[3][tid];
        atomicAdd(stats + tid, t);
    }
}

// ---------------- h0 = relu(norm(nodes) @ W_in + b_in) ----------------
__global__ __launch_bounds__(256) void k_h0(const float* __restrict__ nodes, const float* __restrict__ stats,
                                            const float* __restrict__ Win, const float* __restrict__ bin,
                                            float* __restrict__ h) {
    __shared__ float sW[NFEAT * DD];
    __shared__ float sb[DD];
    __shared__ float sm[8], sr[8];
    int tid = threadIdx.x;
    for (int i = tid; i < NFEAT * DD; i += 256) sW[i] = Win[i];
    if (tid < DD) sb[tid] = bin[tid];
    if (tid < 8) {
        float inv_n = 1.f / (float)(NB * NND);
        float mean = stats[tid] * inv_n;
        float var = stats[8 + tid] * inv_n - mean * mean;
        var = fmaxf(var, 0.f);
        sm[tid] = mean;
        sr[tid] = 1.f / (sqrtf(var) + 1e-8f);
    }
    __syncthreads();
    int gid = blockIdx.x * 256 + tid;
    if (gid >= NB * NND * DD) return;
    int bn = gid >> 7, j = gid & 127;
    const float* p = nodes + (size_t)bn * NFEAT;
    float acc = sb[j];
#pragma unroll
    for (int k = 0; k < 8; ++k) acc += (p[k] - sm[k]) * sr[k] * sW[k * DD + j];
    h[gid] = fmaxf(acc, 0.f);
}

// ---------------- degree count ----------------
__global__ void k_deg(const int* __restrict__ links, int* deg) {
    int gid = blockIdx.x * 256 + threadIdx.x;
    if (gid >= NB * NED) return;
    int b = gid / NED, e = gid % NED;
    int dst = links[b * 2 * NED + NED + e];
    atomicAdd(deg + b * NND + dst, 1);
}

// ---------------- exclusive scan of degrees (per batch block) ----------------
__global__ __launch_bounds__(1024) void k_scan(const int* __restrict__ deg, int* offs, int* cursor) {
    int b = blockIdx.x;
    int tid = threadIdx.x;
    __shared__ int s[1024];
    __shared__ int carry_s;
    if (tid == 0) carry_s = 0;
    __syncthreads();
    for (int c = 0; c < 20; ++c) {
        int i = c * 1024 + tid;
        int v = (i < NND) ? deg[b * NND + i] : 0;
        s[tid] = v;
        __syncthreads();
        for (int off = 1; off < 1024; off <<= 1) {
            int t = (tid >= off) ? s[tid - off] : 0;
            __syncthreads();
            s[tid] += t;
            __syncthreads();
        }
        int incl = s[tid];
        int excl = incl - v;
        int carry = carry_s;
        if (i < NND) {
            offs[b * (NND + 1) + i] = carry + excl;
            cursor[b * NND + i] = carry + excl;
        }
        __syncthreads();
        if (tid == 1023) carry_s = carry + incl;
        __syncthreads();
    }
    if (tid == 0) offs[b * (NND + 1) + NND] = carry_s;
}

// ---------------- CSR fill ----------------
__global__ void k_fill(const int* __restrict__ links, int* cursor, int* csr) {
    int gid = blockIdx.x * 256 + threadIdx.x;
    if (gid >= NB * NED) return;
    int b = gid / NED, e = gid % NED;
    int src = links[b * 2 * NED + e];
    int dst = links[b * 2 * NED + NED + e];
    int p = atomicAdd(cursor + b * NND + dst, 1);
    csr[(size_t)b * NED + p] = src;
}

// ---------------- agg[n] = sum_{src->n} h[src]  (wave per node) ----------------
__global__ __launch_bounds__(256) void k_gather(const float* __restrict__ h, const int* __restrict__ offs,
                                                const int* __restrict__ csr, float* __restrict__ agg) {
    int wid = (blockIdx.x * 256 + threadIdx.x) >> 6;
    int lane = threadIdx.x & 63;
    if (wid >= NB * NND) return;
    int b = wid / NND, n = wid % NND;
    int off0 = offs[b * (NND + 1) + n];
    int off1 = offs[b * (NND + 1) + n + 1];
    float acc0 = 0.f, acc1 = 0.f;
    const float* hb = h + (size_t)b * NND * DD;
    const int* cs = csr + (size_t)b * NED;
    for (int base = off0; base < off1; base += 64) {
        int cnt = min(64, off1 - base);
        int idx = (lane < cnt) ? cs[base + lane] : 0;
        for (int j = 0; j < cnt; ++j) {
            int srcn = __shfl(idx, j, 64);
            const float* hr = hb + (size_t)srcn * DD;
            acc0 += hr[lane];
            acc1 += hr[lane + 64];
        }
    }
    float* ar = agg + (size_t)wid * DD;
    ar[lane] = acc0;
    ar[lane + 64] = acc1;
}

// ---------------- h_new = relu(agg@Wm + h@Ws + b) ----------------
// Column-half split: each block stages a 128x64 slice of Wm and Ws (64 KiB LDS total).
__global__ __launch_bounds__(512) void k_mp(const float* __restrict__ Xa, const float* __restrict__ Xh,
                                            const float* __restrict__ Wm, const float* __restrict__ Ws,
                                            const float* __restrict__ bias, float* __restrict__ out) {
    extern __shared__ float smem[];
    float* sWm = smem;          // 128*64
    float* sWs = smem + 8192;   // 128*64
    int colh = blockIdx.x & 1;
    for (int i = threadIdx.x; i < 8192; i += 512) {
        int r = i >> 6, c = i & 63;
        sWm[i] = Wm[r * DD + colh * 64 + c];
        sWs[i] = Ws[r * DD + colh * 64 + c];
    }
    __syncthreads();
    int lane = threadIdx.x & 63;
    int col = colh * 64 + lane;
    float bcol = bias[col];
    int gw = ((blockIdx.x >> 1) << 3) + (threadIdx.x >> 6);
    for (int g = gw; g < NB * NND; g += 2048) {
        const float* xa = Xa + (size_t)g * DD;
        const float* xh = Xh + (size_t)g * DD;
        float a0 = xa[lane], a1 = xa[lane + 64];
        float h0 = xh[lane], h1 = xh[lane + 64];
        float acc = bcol;
#pragma unroll 8
        for (int k = 0; k < 64; ++k)
            acc += __shfl(a0, k, 64) * sWm[k * 64 + lane] + __shfl(h0, k, 64) * sWs[k * 64 + lane];
#pragma unroll 8
        for (int k = 0; k < 64; ++k)
            acc += __shfl(a1, k, 64) * sWm[(k + 64) * 64 + lane] + __shfl(h1, k, 64) * sWs[(k + 64) * 64 + lane];
        out[(size_t)g * DD + col] = fmaxf(acc, 0.f);
    }
}

// ---------------- a = relu(norm(ad) @ W_ad + b_ad) ----------------
__global__ __launch_bounds__(512) void k_ad(const float* __restrict__ ad, const float* __restrict__ Wad,
                                            const float* __restrict__ bad, float* __restrict__ av) {
    __shared__ float sn[NB * ADF];
    int tid = threadIdx.x;
    if (tid < ADF) {
        float m = 0.f;
        for (int b = 0; b < NB; ++b) m += ad[b * ADF + tid];
        m *= 0.25f;
        float v = 0.f;
        for (int b = 0; b < NB; ++b) { float d = ad[b * ADF + tid] - m; v += d * d; }
        v *= 0.25f;
        float r = 1.f / (sqrtf(v) + 1e-8f);
        for (int b = 0; b < NB; ++b) sn[b * ADF + tid] = (ad[b * ADF + tid] - m) * r;
    }
    __syncthreads();
    int b = tid >> 7, j = tid & 127;
    float acc = bad[j];
#pragma unroll
    for (int k = 0; k < 8; ++k) acc += sn[b * ADF + k] * Wad[k * DD + j];
    av[tid] = fmaxf(acc, 0.f);
}

// ---------------- partial logits: sum_j relu(ph_j) * w_out_j over a 64-col half ----------------
// Column-half split: each block stages a 256x64 slice of W_p (64 KiB LDS).
__global__ __launch_bounds__(512) void k_pair(const float* __restrict__ Xh, const float* __restrict__ av,
                                              const float* __restrict__ Wp, const float* __restrict__ bp,
                                              const float* __restrict__ wout, float* __restrict__ raw) {
    extern __shared__ float smem[];
    float* sW = smem;  // 256*64
    int colh = blockIdx.x & 1;
    for (int i = threadIdx.x; i < 16384; i += 512) {
        int r = i >> 6, c = i & 63;
        sW[i] = Wp[r * DD + colh * 64 + c];
    }
    __syncthreads();
    int lane = threadIdx.x & 63;
    int col = colh * 64 + lane;
    float bcol = bp[col], wcol = wout[col];
    int gw = ((blockIdx.x >> 1) << 3) + (threadIdx.x >> 6);
    for (int g = gw; g < NB * NND; g += 2048) {
        int b = g / NND;
        const float* xh = Xh + (size_t)g * DD;
        const float* xa = av + b * DD;
        float h0 = xh[lane], h1 = xh[lane + 64];
        float a0 = xa[lane], a1 = xa[lane + 64];
        float acc = bcol;
#pragma unroll 8
        for (int k = 0; k < 64; ++k) acc += __shfl(h0, k, 64) * sW[k * 64 + lane];
#pragma unroll 8
        for (int k = 0; k < 64; ++k) acc += __shfl(h1, k, 64) * sW[(k + 64) * 64 + lane];
#pragma unroll 8
        for (int k = 0; k < 64; ++k) acc += __shfl(a0, k, 64) * sW[(k + 128) * 64 + lane];
#pragma unroll 8
        for (int k = 0; k < 64; ++k) acc += __shfl(a1, k, 64) * sW[(k + 192) * 64 + lane];
        float v = fmaxf(acc, 0.f) * wcol;
        for (int off = 32; off; off >>= 1) v += __shfl_xor(v, off, 64);
        if (lane == 0) atomicAdd(raw + g, v);
    }
}

// ---------------- apply mask ----------------
__global__ void k_masklog(const float* __restrict__ raw, const int* __restrict__ mc, float* __restrict__ logits) {
    int g = blockIdx.x * 256 + threadIdx.x;
    if (g >= NB * NND) return;
    logits[g] = mc[g] ? raw[g] : NEGINF;
}

// ---------------- softmax max ----------------
__global__ __launch_bounds__(256) void k_max(const float* __restrict__ logits, unsigned* mtrans) {
    int b = blockIdx.x >> 6, chunk = blockIdx.x & 63, tid = threadIdx.x;
    float m = -3.0e38f;
    for (int i = chunk * 256 + tid; i < NND; i += 64 * 256) m = fmaxf(m, logits[b * NND + i]);
    for (int off = 32; off; off >>= 1) m = fmaxf(m, __shfl_xor(m, off, 64));
    __shared__ float lm[4];
    if ((tid & 63) == 0) lm[tid >> 6] = m;
    __syncthreads();
    if (tid == 0) {
        m = fmaxf(fmaxf(lm[0], lm[1]), fmaxf(lm[2], lm[3]));
        atomicMax(mtrans + b, ftrans(m));
    }
}

// ---------------- softmax denom ----------------
__global__ __launch_bounds__(256) void k_sumexp(const float* __restrict__ logits, const unsigned* __restrict__ mtrans,
                                                float* S) {
    int b = blockIdx.x >> 6, chunk = blockIdx.x & 63, tid = threadIdx.x;
    float m = finv(mtrans[b]);
    float s = 0.f;
    for (int i = chunk * 256 + tid; i < NND; i += 64 * 256) s += expf(logits[b * NND + i] - m);
    for (int off = 32; off; off >>= 1) s += __shfl_xor(s, off, 64);
    __shared__ float ls[4];
    if ((tid & 63) == 0) ls[tid >> 6] = s;
    __syncthreads();
    if (tid == 0) atomicAdd(S + b, ls[0] + ls[1] + ls[2] + ls[3]);
}

// ---------------- context accumulation: ctx = sum exp(l-m) * h ----------------
__global__ __launch_bounds__(128) void k_ctx(const float* __restrict__ logits, const float* __restrict__ h,
                                             const unsigned* __restrict__ mtrans, float* ctx) {
    int b = blockIdx.x >> 6, chunk = blockIdx.x & 63, j = threadIdx.x;
    float m = finv(mtrans[b]);
    float c = 0.f;
    for (int n = chunk; n < NND; n += 64) {
        float w = expf(logits[b * NND + n] - m);
        c += w * h[((size_t)b * NND + n) * DD + j];
    }
    atomicAdd(ctx + b * DD + j, c);
}

// ---------------- log_probs out ----------------
__global__ __launch_bounds__(256) void k_final(const float* __restrict__ logits, const unsigned* __restrict__ mtrans,
                                               const float* __restrict__ S, float* __restrict__ out) {
    int g = blockIdx.x * 256 + threadIdx.x;
    if (g >= NB * NND) return;
    int b = g / NND;
    out[g] = logits[g] - finv(mtrans[b]) - logf(S[b]);
}

// ---------------- value head ----------------
__global__ __launch_bounds__(512) void k_value(const float* __restrict__ ctx, const float* __restrict__ S,
                                               const float* __restrict__ av, const float* __restrict__ Wv,
                                               const float* __restrict__ bv, const float* __restrict__ wvo,
                                               float* __restrict__ out) {
    int tid = threadIdx.x, b = tid >> 7, j = tid & 127;
    float sb = S[b];
    float s1 = 0.f, s2 = 0.f;
    for (int k = 0; k < 128; ++k) s1 += ctx[b * DD + k] * Wv[k * DD + j];
    for (int k = 0; k < 128; ++k) s2 += av[b * DD + k] * Wv[(128 + k) * DD + j];
    float acc = bv[j] + s1 / sb + s2;
    float p = fmaxf(acc, 0.f) * wvo[j];
    __shared__ float red[512];
    red[tid] = p;
    __syncthreads();
    for (int off = 64; off; off >>= 1) {
        if (j < off) red[tid] += red[tid + off];
        __syncthreads();
    }
    if (j == 0) out[NB * NND + b] = red[tid];
}

extern "C" void kernel_launch(void* const* d_in, const int* in_sizes, int n_in,
                              void* d_out, int out_size, void* d_ws, size_t ws_size,
                              hipStream_t stream) {
    const float* nodes = (const float*)d_in[0];
    const int* links = (const int*)d_in[1];
    const void* mask = d_in[2];
    const float* ad = (const float*)d_in[3];
    const float* Win = (const float*)d_in[4];
    const float* bin = (const float*)d_in[5];
    const float* Wm1 = (const float*)d_in[6];
    const float* Ws1 = (const float*)d_in[7];
    const float* b1 = (const float*)d_in[8];
    const float* Wm2 = (const float*)d_in[9];
    const float* Ws2 = (const float*)d_in[10];
    const float* b2 = (const float*)d_in[11];
    const float* Wad = (const float*)d_in[12];
    const float* bad = (const float*)d_in[13];
    const float* Wp = (const float*)d_in[14];
    const float* bp = (const float*)d_in[15];
    const float* wout = (const float*)d_in[16];
    const float* Wv = (const float*)d_in[17];
    const float* bv = (const float*)d_in[18];
    const float* wvo = (const float*)d_in[19];
    float* out = (float*)d_out;

    float* buf0 = (float*)d_ws;                 // 10,240,000
    float* buf1 = buf0 + 10240000;              // 10,240,000
    float* logits = buf1 + 10240000;            // 80,000
    float* raw = logits + 80000;                // 80,000
    float* stats = raw + 80000;                 // 64
    float* a_vec = stats + 64;                  // 512
    float* Sexp = a_vec + 512;                  // 64
    float* ctx = Sexp + 64;                     // 512
    unsigned* mtrans = (unsigned*)(ctx + 512);  // 64
    int* deg = (int*)(mtrans + 64);             // 80,000
    int* offs = deg + 80000;                    // 80,064
    int* cursor = offs + 80064;                 // 80,000
    int* csr = cursor + 80000;                  // 1,280,000
    int* mc = csr + 1280000;                    // 80,000
    int* flag = mc + 80000;                     // 64

    k_init<<<313, 256, 0, stream>>>(stats, deg, mtrans, Sexp, ctx, raw);
    k_flag<<<1, 256, 0, stream>>>((const unsigned char*)mask, flag);
    k_maskc<<<313, 256, 0, stream>>>(mask, flag, mc);
    k_stats<<<256, 256, 0, stream>>>(nodes, stats);
    k_h0<<<40000, 256, 0, stream>>>(nodes, stats, Win, bin, buf0);
    k_deg<<<5000, 256, 0, stream>>>(links, deg);
    k_scan<<<4, 1024, 0, stream>>>(deg, offs, cursor);
    k_fill<<<5000, 256, 0, stream>>>(links, cursor, csr);

    k_gather<<<20000, 256, 0, stream>>>(buf0, offs, csr, buf1);
    k_mp<<<512, 512, 65536, stream>>>(buf1, buf0, Wm1, Ws1, b1, buf1);
    k_gather<<<20000, 256, 0, stream>>>(buf1, offs, csr, buf0);
    k_mp<<<512, 512, 65536, stream>>>(buf0, buf1, Wm2, Ws2, b2, buf0);

    k_ad<<<1, 512, 0, stream>>>(ad, Wad, bad, a_vec);
    k_pair<<<512, 512, 65536, stream>>>(buf0, a_vec, Wp, bp, wout, raw);
    k_masklog<<<313, 256, 0, stream>>>(raw, mc, logits);

    k_max<<<256, 256, 0, stream>>>(logits, mtrans);
    k_sumexp<<<256, 256, 0, stream>>>(logits, mtrans, Sexp);
    k_ctx<<<256, 128, 0, stream>>>(logits, buf0, mtrans, ctx);
    k_final<<<313, 256, 0, stream>>>(logits, mtrans, Sexp, out);
    k_value<<<1, 512, 0, stream>>>(ctx, Sexp, a_vec, Wv, bv, wvo, out);
}

// Round 3
// 545.044 us; speedup vs baseline: 4.0954x; 4.0954x over previous
//
#include <hip/hip_runtime.h>
#include <hip/hip_bf16.h>
#include <math.h>

#define NND 20000
#define NED 320000
#define NB 4
#define NFEAT 8
#define ADF 8
#define DD 128
#define MROWS (NB * NND)
#define NEGINF -1000000000.0f

typedef __attribute__((ext_vector_type(8))) short short8;
typedef __attribute__((ext_vector_type(4))) float f32x4;

__device__ __forceinline__ unsigned ftrans(float f) {
    unsigned u = __float_as_uint(f);
    return (u & 0x80000000u) ? ~u : (u | 0x80000000u);
}
__device__ __forceinline__ float finv(unsigned t) {
    unsigned u = (t & 0x80000000u) ? (t & 0x7fffffffu) : ~t;
    return __uint_as_float(u);
}
__device__ __forceinline__ unsigned short f2bf(float f) {  // RNE, finite inputs
    unsigned u = __float_as_uint(f);
    unsigned r = u + 0x7fffu + ((u >> 16) & 1u);
    return (unsigned short)(r >> 16);
}
__device__ __forceinline__ float bf2f(unsigned short b) {
    return __uint_as_float(((unsigned)b) << 16);
}

// ---------------- init scratch accumulators ----------------
__global__ void k_init(float* stats, int* deg, unsigned* mtrans, float* S, float* ctx) {
    int i = blockIdx.x * 256 + threadIdx.x;
    if (i < 16) stats[i] = 0.f;
    if (i < NB * NND) deg[i] = 0;
    if (i < NB) { mtrans[i] = 0u; S[i] = 0.f; }
    if (i < NB * DD) ctx[i] = 0.f;
}

// ---------------- mask dtype detection (bool/uint8 vs int32) ----------------
__global__ void k_flag(const unsigned char* __restrict__ m, int* flag) {
    __shared__ int any;
    if (threadIdx.x == 0) any = 0;
    __syncthreads();
    int found = 0;
    for (int p = threadIdx.x; p < 4096; p += 256)
        if ((p & 3) && m[p]) found = 1;
    if (found) atomicOr(&any, 1);
    __syncthreads();
    if (threadIdx.x == 0) *flag = any;
}

__global__ void k_maskc(const void* __restrict__ m, const int* __restrict__ flag, int* __restrict__ mc) {
    int g = blockIdx.x * 256 + threadIdx.x;
    if (g >= NB * NND) return;
    int f = *flag;
    mc[g] = f ? (int)((const unsigned char*)m)[g] : ((const int*)m)[g];
}

// ---------------- weight prep: B^T bf16, XOR-swizzled 16B chunks ----------------
// Bt_sw layout: 128 rows (n = output col), each row 256 bf16 (k); chunk (16B=8 elems)
// index stored at (mm ^ (n&7)). Matrix 0: [Wm1;Ws1], 1: [Wm2;Ws2], 2: Wp.
__global__ void k_prep(const float* __restrict__ Wm1, const float* __restrict__ Ws1,
                       const float* __restrict__ Wm2, const float* __restrict__ Ws2,
                       const float* __restrict__ Wp,
                       unsigned short* __restrict__ B1t, unsigned short* __restrict__ B2t,
                       unsigned short* __restrict__ Bpt) {
    int m = blockIdx.x;
    const float* S0 = (m == 0) ? Wm1 : ((m == 1) ? Wm2 : Wp);
    const float* S1 = (m == 0) ? Ws1 : ((m == 1) ? Ws2 : (Wp + 128 * DD));
    unsigned short* D = (m == 0) ? B1t : ((m == 1) ? B2t : Bpt);
    for (int idx = threadIdx.x; idx < 128 * 32; idx += 256) {
        int n = idx >> 5;    // output col 0..127
        int mm = idx & 31;   // logical 16B chunk (8 k-elems)
        short8 pk;
#pragma unroll
        for (int j = 0; j < 8; ++j) {
            int k = mm * 8 + j;
            float v = (k < 128) ? S0[k * DD + n] : S1[(k - 128) * DD + n];
            pk[j] = (short)f2bf(v);
        }
        int mst = mm ^ (n & 7);
        *(short8*)(D + n * 256 + mst * 8) = pk;
    }
}

// ---------------- node feature mean/var sums ----------------
__global__ __launch_bounds__(256) void k_stats(const float* __restrict__ nodes, float* stats) {
    int tid = threadIdx.x;
    int gid = blockIdx.x * 256 + tid;
    float s[8] = {0.f,0.f,0.f,0.f,0.f,0.f,0.f,0.f};
    float q[8] = {0.f,0.f,0.f,0.f,0.f,0.f,0.f,0.f};
    for (int r = gid; r < NB * NND; r += 256 * 256) {
        const float* p = nodes + (size_t)r * NFEAT;
#pragma unroll
        for (int k = 0; k < 8; ++k) { float v = p[k]; s[k] += v; q[k] += v * v; }
    }
#pragma unroll
    for (int k = 0; k < 8; ++k) {
        for (int off = 32; off; off >>= 1) {
            s[k] += __shfl_xor(s[k], off, 64);
            q[k] += __shfl_xor(q[k], off, 64);
        }
    }
    __shared__ float ls[4][16];
    int w = tid >> 6, lane = tid & 63;
    if (lane == 0) {
#pragma unroll
        for (int k = 0; k < 8; ++k) { ls[w][k] = s[k]; ls[w][8 + k] = q[k]; }
    }
    __syncthreads();
    if (tid < 16) {
        float t = ls[0][tid] + ls[1][tid] + ls[2][tid] + ls[3][tid];
        atomicAdd(stats + tid, t);
    }
}

// ---------------- h0 = relu(norm(nodes) @ W_in + b_in) -> bf16 ----------------
__global__ __launch_bounds__(256) void k_h0(const float* __restrict__ nodes, const float* __restrict__ stats,
                                            const float* __restrict__ Win, const float* __restrict__ bin,
                                            unsigned short* __restrict__ h) {
    __shared__ float sW[NFEAT * DD];
    __shared__ float sb[DD];
    __shared__ float sm[8], sr[8];
    int tid = threadIdx.x;
    for (int i = tid; i < NFEAT * DD; i += 256) sW[i] = Win[i];
    if (tid < DD) sb[tid] = bin[tid];
    if (tid < 8) {
        float inv_n = 1.f / (float)(NB * NND);
        float mean = stats[tid] * inv_n;
        float var = stats[8 + tid] * inv_n - mean * mean;
        var = fmaxf(var, 0.f);
        sm[tid] = mean;
        sr[tid] = 1.f / (sqrtf(var) + 1e-8f);
    }
    __syncthreads();
    int gid = blockIdx.x * 256 + tid;
    if (gid >= NB * NND * DD) return;
    int bn = gid >> 7, j = gid & 127;
    const float* p = nodes + (size_t)bn * NFEAT;
    float acc = sb[j];
#pragma unroll
    for (int k = 0; k < 8; ++k) acc += (p[k] - sm[k]) * sr[k] * sW[k * DD + j];
    h[gid] = f2bf(fmaxf(acc, 0.f));
}

// ---------------- degree count ----------------
__global__ void k_deg(const int* __restrict__ links, int* deg) {
    int gid = blockIdx.x * 256 + threadIdx.x;
    if (gid >= NB * NED) return;
    int b = gid / NED, e = gid % NED;
    int dst = links[b * 2 * NED + NED + e];
    atomicAdd(deg + b * NND + dst, 1);
}

// ---------------- exclusive scan of degrees (wave-shfl version) ----------------
__global__ __launch_bounds__(1024) void k_scan(const int* __restrict__ deg, int* offs, int* cursor) {
    int b = blockIdx.x;
    int tid = threadIdx.x, lane = tid & 63, wv = tid >> 6;
    __shared__ int wsum[16], wexcl[16];
    __shared__ int carry_s;
    if (tid == 0) carry_s = 0;
    __syncthreads();
    for (int c = 0; c < 20; ++c) {
        int i = c * 1024 + tid;
        int v = (i < NND) ? deg[b * NND + i] : 0;
        int x = v;
#pragma unroll
        for (int d = 1; d < 64; d <<= 1) {
            int t = __shfl_up(x, d, 64);
            if (lane >= d) x += t;
        }
        if (lane == 63) wsum[wv] = x;
        __syncthreads();
        if (wv == 0) {
            int s = (lane < 16) ? wsum[lane] : 0;
#pragma unroll
            for (int d = 1; d < 16; d <<= 1) {
                int t = __shfl_up(s, d, 64);
                if (lane >= d) s += t;
            }
            if (lane < 16) wexcl[lane] = s - wsum[lane];
        }
        __syncthreads();
        int carry = carry_s;
        int excl = carry + wexcl[wv] + (x - v);
        if (i < NND) {
            offs[b * (NND + 1) + i] = excl;
            cursor[b * NND + i] = excl;
        }
        __syncthreads();
        if (tid == 0) carry_s = carry + wexcl[15] + wsum[15];
        __syncthreads();
    }
    if (tid == 0) offs[b * (NND + 1) + NND] = carry_s;
}

// ---------------- CSR fill ----------------
__global__ void k_fill(const int* __restrict__ links, int* cursor, int* csr) {
    int gid = blockIdx.x * 256 + threadIdx.x;
    if (gid >= NB * NED) return;
    int b = gid / NED, e = gid % NED;
    int src = links[b * 2 * NED + e];
    int dst = links[b * 2 * NED + NED + e];
    int p = atomicAdd(cursor + b * NND + dst, 1);
    csr[(size_t)b * NED + p] = src;
}

// ---------------- agg[n] = sum_{src->n} h[src]  (wave per node, bf16 io) ----------------
__global__ __launch_bounds__(256) void k_gather(const unsigned short* __restrict__ h, const int* __restrict__ offs,
                                                const int* __restrict__ csr, unsigned short* __restrict__ agg) {
    int wid = (blockIdx.x * 256 + threadIdx.x) >> 6;
    int lane = threadIdx.x & 63;
    if (wid >= NB * NND) return;
    int b = wid / NND, n = wid % NND;
    int off0 = offs[b * (NND + 1) + n];
    int off1 = offs[b * (NND + 1) + n + 1];
    float acc0 = 0.f, acc1 = 0.f;
    const unsigned* hb = (const unsigned*)(h + (size_t)b * NND * DD);
    const int* cs = csr + (size_t)b * NED;
    for (int base = off0; base < off1; base += 64) {
        int cnt = min(64, off1 - base);
        int idx = (lane < cnt) ? cs[base + lane] : 0;
        for (int j = 0; j < cnt; ++j) {
            int srcn = __shfl(idx, j, 64);
            unsigned v = hb[srcn * 64 + lane];
            acc0 += __uint_as_float(v << 16);
            acc1 += __uint_as_float(v & 0xffff0000u);
        }
    }
    unsigned* ar = (unsigned*)(agg + (size_t)wid * DD);
    ar[lane] = ((unsigned)f2bf(acc1) << 16) | (unsigned)f2bf(acc0);
}

// ---------------- MFMA: h_new = relu([agg,h] @ Bt + bias) -> bf16 ----------------
// Block 256 = 4 waves, each wave owns 64 rows (4x 16-row stripes).
// Out may alias Xh (wave-exclusive rows; reads precede stores in wave program order).
__global__ __launch_bounds__(256) void k_mp_mfma(const unsigned short* __restrict__ Xa,
                                                 const unsigned short* __restrict__ Xh,
                                                 const unsigned short* __restrict__ Bt,
                                                 const float* __restrict__ bias,
                                                 unsigned short* __restrict__ Out) {
    __shared__ unsigned short sB[128 * 256];  // 64 KiB, staged linear (pre-swizzled)
    {
        const uint4* s4 = (const uint4*)Bt;
        uint4* d4 = (uint4*)sB;
        for (int i = threadIdx.x; i < 4096; i += 256) d4[i] = s4[i];
    }
    __syncthreads();
    int wave = threadIdx.x >> 6, lane = threadIdx.x & 63;
    int row0 = blockIdx.x * 256 + wave * 64;
    int arow = lane & 15, kgrp = lane >> 4;
    f32x4 acc[4][8];
#pragma unroll
    for (int s = 0; s < 4; ++s)
#pragma unroll
        for (int c = 0; c < 8; ++c) acc[s][c] = (f32x4){0.f, 0.f, 0.f, 0.f};
    const unsigned short* aptr[4];
    const unsigned short* hptr[4];
#pragma unroll
    for (int s = 0; s < 4; ++s) {
        int r = row0 + s * 16 + arow;
        int rr = (r < MROWS) ? r : (MROWS - 1);
        aptr[s] = Xa + (size_t)rr * DD + kgrp * 8;
        hptr[s] = Xh + (size_t)rr * DD + kgrp * 8;
    }
#pragma unroll
    for (int ks = 0; ks < 8; ++ks) {
        short8 a[4];
#pragma unroll
        for (int s = 0; s < 4; ++s)
            a[s] = (ks < 4) ? *(const short8*)(aptr[s] + ks * 32)
                            : *(const short8*)(hptr[s] + (ks - 4) * 32);
#pragma unroll
        for (int c = 0; c < 8; ++c) {
            int n = c * 16 + arow;
            int mst = (ks * 4 + kgrp) ^ (n & 7);
            short8 bfr = *(const short8*)(sB + n * 256 + mst * 8);
#pragma unroll
            for (int s = 0; s < 4; ++s)
                acc[s][c] = __builtin_amdgcn_mfma_f32_16x16x32_bf16(a[s], bfr, acc[s][c], 0, 0, 0);
        }
    }
    float bcol[8];
#pragma unroll
    for (int c = 0; c < 8; ++c) bcol[c] = bias[c * 16 + arow];
#pragma unroll
    for (int s = 0; s < 4; ++s) {
#pragma unroll
        for (int j = 0; j < 4; ++j) {
            int r = row0 + s * 16 + kgrp * 4 + j;
            if (r < MROWS) {
                unsigned short* orow = Out + (size_t)r * DD;
#pragma unroll
                for (int c = 0; c < 8; ++c) {
                    float v = fmaxf(acc[s][c][j] + bcol[c], 0.f);
                    orow[c * 16 + arow] = f2bf(v);
                }
            }
        }
    }
}

// ---------------- a = relu(norm(ad) @ W_ad + b_ad) (fp32 + bf16 copies) ----------------
__global__ __launch_bounds__(512) void k_ad(const float* __restrict__ ad, const float* __restrict__ Wad,
                                            const float* __restrict__ bad, float* __restrict__ av,
                                            unsigned short* __restrict__ av_bf) {
    __shared__ float sn[NB * ADF];
    int tid = threadIdx.x;
    if (tid < ADF) {
        float m = 0.f;
        for (int b = 0; b < NB; ++b) m += ad[b * ADF + tid];
        m *= 0.25f;
        float v = 0.f;
        for (int b = 0; b < NB; ++b) { float d = ad[b * ADF + tid] - m; v += d * d; }
        v *= 0.25f;
        float r = 1.f / (sqrtf(v) + 1e-8f);
        for (int b = 0; b < NB; ++b) sn[b * ADF + tid] = (ad[b * ADF + tid] - m) * r;
    }
    __syncthreads();
    int b = tid >> 7, j = tid & 127;
    float acc = bad[j];
#pragma unroll
    for (int k = 0; k < 8; ++k) acc += sn[b * ADF + k] * Wad[k * DD + j];
    float rl = fmaxf(acc, 0.f);
    av[tid] = rl;
    av_bf[tid] = f2bf(rl);
}

// ---------------- MFMA pair+dot: logits = mask ? relu([h,a]@Wp+bp).wout : NEGINF ----------------
__global__ __launch_bounds__(256) void k_pair_mfma(const unsigned short* __restrict__ Xh,
                                                   const unsigned short* __restrict__ Abf,
                                                   const unsigned short* __restrict__ Bt,
                                                   const float* __restrict__ bp,
                                                   const float* __restrict__ wout,
                                                   const int* __restrict__ mc,
                                                   float* __restrict__ logits) {
    __shared__ unsigned short sB[128 * 256];
    {
        const uint4* s4 = (const uint4*)Bt;
        uint4* d4 = (uint4*)sB;
        for (int i = threadIdx.x; i < 4096; i += 256) d4[i] = s4[i];
    }
    __syncthreads();
    int wave = threadIdx.x >> 6, lane = threadIdx.x & 63;
    int row0 = blockIdx.x * 256 + wave * 64;
    int arow = lane & 15, kgrp = lane >> 4;
    f32x4 acc[4][8];
#pragma unroll
    for (int s = 0; s < 4; ++s)
#pragma unroll
        for (int c = 0; c < 8; ++c) acc[s][c] = (f32x4){0.f, 0.f, 0.f, 0.f};
    const unsigned short* hptr[4];
    const unsigned short* aptr[4];
#pragma unroll
    for (int s = 0; s < 4; ++s) {
        int r = row0 + s * 16 + arow;
        int rr = (r < MROWS) ? r : (MROWS - 1);
        hptr[s] = Xh + (size_t)rr * DD + kgrp * 8;
        aptr[s] = Abf + (size_t)(rr / NND) * DD + kgrp * 8;
    }
#pragma unroll
    for (int ks = 0; ks < 8; ++ks) {
        short8 a[4];
#pragma unroll
        for (int s = 0; s < 4; ++s)
            a[s] = (ks < 4) ? *(const short8*)(hptr[s] + ks * 32)
                            : *(const short8*)(aptr[s] + (ks - 4) * 32);
#pragma unroll
        for (int c = 0; c < 8; ++c) {
            int n = c * 16 + arow;
            int mst = (ks * 4 + kgrp) ^ (n & 7);
            short8 bfr = *(const short8*)(sB + n * 256 + mst * 8);
#pragma unroll
            for (int s = 0; s < 4; ++s)
                acc[s][c] = __builtin_amdgcn_mfma_f32_16x16x32_bf16(a[s], bfr, acc[s][c], 0, 0, 0);
        }
    }
    float bpc[8], wc[8];
#pragma unroll
    for (int c = 0; c < 8; ++c) {
        int col = c * 16 + arow;
        bpc[c] = bp[col];
        wc[c] = wout[col];
    }
#pragma unroll
    for (int s = 0; s < 4; ++s) {
#pragma unroll
        for (int j = 0; j < 4; ++j) {
            float v = 0.f;
#pragma unroll
            for (int c = 0; c < 8; ++c)
                v += fmaxf(acc[s][c][j] + bpc[c], 0.f) * wc[c];
            v += __shfl_xor(v, 1, 64);
            v += __shfl_xor(v, 2, 64);
            v += __shfl_xor(v, 4, 64);
            v += __shfl_xor(v, 8, 64);
            int r = row0 + s * 16 + kgrp * 4 + j;
            if (arow == 0 && r < MROWS)
                logits[r] = mc[r] ? v : NEGINF;
        }
    }
}

// ---------------- softmax max ----------------
__global__ __launch_bounds__(256) void k_max(const float* __restrict__ logits, unsigned* mtrans) {
    int b = blockIdx.x >> 6, chunk = blockIdx.x & 63, tid = threadIdx.x;
    float m = -3.0e38f;
    for (int i = chunk * 256 + tid; i < NND; i += 64 * 256) m = fmaxf(m, logits[b * NND + i]);
    for (int off = 32; off; off >>= 1) m = fmaxf(m, __shfl_xor(m, off, 64));
    __shared__ float lm[4];
    if ((tid & 63) == 0) lm[tid >> 6] = m;
    __syncthreads();
    if (tid == 0) {
        m = fmaxf(fmaxf(lm[0], lm[1]), fmaxf(lm[2], lm[3]));
        atomicMax(mtrans + b, ftrans(m));
    }
}

// ---------------- softmax denom ----------------
__global__ __launch_bounds__(256) void k_sumexp(const float* __restrict__ logits, const unsigned* __restrict__ mtrans,
                                                float* S) {
    int b = blockIdx.x >> 6, chunk = blockIdx.x & 63, tid = threadIdx.x;
    float m = finv(mtrans[b]);
    float s = 0.f;
    for (int i = chunk * 256 + tid; i < NND; i += 64 * 256) s += expf(logits[b * NND + i] - m);
    for (int off = 32; off; off >>= 1) s += __shfl_xor(s, off, 64);
    __shared__ float ls[4];
    if ((tid & 63) == 0) ls[tid >> 6] = s;
    __syncthreads();
    if (tid == 0) atomicAdd(S + b, ls[0] + ls[1] + ls[2] + ls[3]);
}

// ---------------- context: ctx = sum exp(l-m) * h (bf16 h) ----------------
__global__ __launch_bounds__(128) void k_ctx(const float* __restrict__ logits, const unsigned short* __restrict__ h,
                                             const unsigned* __restrict__ mtrans, float* ctx) {
    int b = blockIdx.x >> 6, chunk = blockIdx.x & 63, j = threadIdx.x;
    float m = finv(mtrans[b]);
    float c = 0.f;
    for (int n = chunk; n < NND; n += 64) {
        float w = expf(logits[b * NND + n] - m);
        c += w * bf2f(h[((size_t)b * NND + n) * DD + j]);
    }
    atomicAdd(ctx + b * DD + j, c);
}

// ---------------- log_probs out ----------------
__global__ __launch_bounds__(256) void k_final(const float* __restrict__ logits, const unsigned* __restrict__ mtrans,
                                               const float* __restrict__ S, float* __restrict__ out) {
    int g = blockIdx.x * 256 + threadIdx.x;
    if (g >= NB * NND) return;
    int b = g / NND;
    out[g] = logits[g] - finv(mtrans[b]) - logf(S[b]);
}

// ---------------- value head ----------------
__global__ __launch_bounds__(512) void k_value(const float* __restrict__ ctx, const float* __restrict__ S,
                                               const float* __restrict__ av, const float* __restrict__ Wv,
                                               const float* __restrict__ bv, const float* __restrict__ wvo,
                                               float* __restrict__ out) {
    int tid = threadIdx.x, b = tid >> 7, j = tid & 127;
    float sb = S[b];
    float s1 = 0.f, s2 = 0.f;
    for (int k = 0; k < 128; ++k) s1 += ctx[b * DD + k] * Wv[k * DD + j];
    for (int k = 0; k < 128; ++k) s2 += av[b * DD + k] * Wv[(128 + k) * DD + j];
    float acc = bv[j] + s1 / sb + s2;
    float p = fmaxf(acc, 0.f) * wvo[j];
    __shared__ float red[512];
    red[tid] = p;
    __syncthreads();
    for (int off = 64; off; off >>= 1) {
        if (j < off) red[tid] += red[tid + off];
        __syncthreads();
    }
    if (j == 0) out[NB * NND + b] = red[tid];
}

extern "C" void kernel_launch(void* const* d_in, const int* in_sizes, int n_in,
                              void* d_out, int out_size, void* d_ws, size_t ws_size,
                              hipStream_t stream) {
    const float* nodes = (const float*)d_in[0];
    const int* links = (const int*)d_in[1];
    const void* mask = d_in[2];
    const float* ad = (const float*)d_in[3];
    const float* Win = (const float*)d_in[4];
    const float* bin = (const float*)d_in[5];
    const float* Wm1 = (const float*)d_in[6];
    const float* Ws1 = (const float*)d_in[7];
    const float* b1 = (const float*)d_in[8];
    const float* Wm2 = (const float*)d_in[9];
    const float* Ws2 = (const float*)d_in[10];
    const float* b2 = (const float*)d_in[11];
    const float* Wad = (const float*)d_in[12];
    const float* bad = (const float*)d_in[13];
    const float* Wp = (const float*)d_in[14];
    const float* bp = (const float*)d_in[15];
    const float* wout = (const float*)d_in[16];
    const float* Wv = (const float*)d_in[17];
    const float* bv = (const float*)d_in[18];
    const float* wvo = (const float*)d_in[19];
    float* out = (float*)d_out;

    unsigned short* hA = (unsigned short*)d_ws;     // 10,240,000 ush (h0/h1/h2)
    unsigned short* hB = hA + 10240000;             // 10,240,000 ush (agg)
    unsigned short* B1t = hB + 10240000;            // 32768
    unsigned short* B2t = B1t + 32768;              // 32768
    unsigned short* Bpt = B2t + 32768;              // 32768
    unsigned short* a_bf = Bpt + 32768;             // 512
    float* logits = (float*)(a_bf + 512);           // 80,000
    float* stats = logits + 80000;                  // 64
    float* a_vec = stats + 64;                      // 512
    float* Sexp = a_vec + 512;                      // 64
    float* ctxb = Sexp + 64;                        // 512
    unsigned* mtrans = (unsigned*)(ctxb + 512);     // 64
    int* deg = (int*)(mtrans + 64);                 // 80,000
    int* offs = deg + 80000;                        // 80,064
    int* cursor = offs + 80064;                     // 80,000
    int* csr = cursor + 80000;                      // 1,280,000
    int* mc = csr + 1280000;                        // 80,000
    int* flag = mc + 80000;                         // 64

    k_init<<<313, 256, 0, stream>>>(stats, deg, mtrans, Sexp, ctxb);
    k_flag<<<1, 256, 0, stream>>>((const unsigned char*)mask, flag);
    k_maskc<<<313, 256, 0, stream>>>(mask, flag, mc);
    k_prep<<<3, 256, 0, stream>>>(Wm1, Ws1, Wm2, Ws2, Wp, B1t, B2t, Bpt);
    k_stats<<<256, 256, 0, stream>>>(nodes, stats);
    k_h0<<<40000, 256, 0, stream>>>(nodes, stats, Win, bin, hA);
    k_deg<<<5000, 256, 0, stream>>>(links, deg);
    k_scan<<<4, 1024, 0, stream>>>(deg, offs, cursor);
    k_fill<<<5000, 256, 0, stream>>>(links, cursor, csr);

    k_gather<<<20000, 256, 0, stream>>>(hA, offs, csr, hB);
    k_mp_mfma<<<313, 256, 0, stream>>>(hB, hA, B1t, b1, hA);
    k_gather<<<20000, 256, 0, stream>>>(hA, offs, csr, hB);
    k_mp_mfma<<<313, 256, 0, stream>>>(hB, hA, B2t, b2, hA);

    k_ad<<<1, 512, 0, stream>>>(ad, Wad, bad, a_vec, a_bf);
    k_pair_mfma<<<313, 256, 0, stream>>>(hA, a_bf, Bpt, bp, wout, mc, logits);

    k_max<<<256, 256, 0, stream>>>(logits, mtrans);
    k_sumexp<<<256, 256, 0, stream>>>(logits, mtrans, Sexp);
    k_ctx<<<256, 128, 0, stream>>>(logits, hA, mtrans, ctxb);
    k_final<<<313, 256, 0, stream>>>(logits, mtrans, Sexp, out);
    k_value<<<1, 512, 0, stream>>>(ctxb, Sexp, a_vec, Wv, bv, wvo, out);
}

// Round 4
// 398.217 us; speedup vs baseline: 5.6055x; 1.3687x over previous
//
#include <hip/hip_runtime.h>
#include <hip/hip_bf16.h>
#include <math.h>

#define NND 20000
#define NED 320000
#define NB 4
#define NFEAT 8
#define ADF 8
#define DD 128
#define MROWS (NB * NND)
#define NEGINF -1000000000.0f

typedef __attribute__((ext_vector_type(8))) short short8;
typedef __attribute__((ext_vector_type(4))) float f32x4;

__device__ __forceinline__ unsigned ftrans(float f) {
    unsigned u = __float_as_uint(f);
    return (u & 0x80000000u) ? ~u : (u | 0x80000000u);
}
__device__ __forceinline__ float finv(unsigned t) {
    unsigned u = (t & 0x80000000u) ? (t & 0x7fffffffu) : ~t;
    return __uint_as_float(u);
}
__device__ __forceinline__ unsigned short f2bf(float f) {  // RNE, finite inputs
    unsigned u = __float_as_uint(f);
    unsigned r = u + 0x7fffu + ((u >> 16) & 1u);
    return (unsigned short)(r >> 16);
}
__device__ __forceinline__ float bf2f(unsigned short b) {
    return __uint_as_float(((unsigned)b) << 16);
}
__device__ __forceinline__ void unpack8(uint4 v, float* f) {
    f[0] = __uint_as_float(v.x << 16); f[1] = __uint_as_float(v.x & 0xffff0000u);
    f[2] = __uint_as_float(v.y << 16); f[3] = __uint_as_float(v.y & 0xffff0000u);
    f[4] = __uint_as_float(v.z << 16); f[5] = __uint_as_float(v.z & 0xffff0000u);
    f[6] = __uint_as_float(v.w << 16); f[7] = __uint_as_float(v.w & 0xffff0000u);
}

// ---------------- init scratch accumulators ----------------
__global__ void k_init(float* stats, int* deg, unsigned* mtrans, float* S, float* ctx) {
    int i = blockIdx.x * 256 + threadIdx.x;
    if (i < 16) stats[i] = 0.f;
    if (i < NB * NND) deg[i] = 0;
    if (i < NB) { mtrans[i] = 0u; S[i] = 0.f; }
    if (i < NB * DD) ctx[i] = 0.f;
}

// ---------------- mask dtype detection (bool/uint8 vs int32) ----------------
__global__ void k_flag(const unsigned char* __restrict__ m, int* flag) {
    __shared__ int any;
    if (threadIdx.x == 0) any = 0;
    __syncthreads();
    int found = 0;
    for (int p = threadIdx.x; p < 4096; p += 256)
        if ((p & 3) && m[p]) found = 1;
    if (found) atomicOr(&any, 1);
    __syncthreads();
    if (threadIdx.x == 0) *flag = any;
}

__global__ void k_maskc(const void* __restrict__ m, const int* __restrict__ flag, int* __restrict__ mc) {
    int g = blockIdx.x * 256 + threadIdx.x;
    if (g >= NB * NND) return;
    int f = *flag;
    mc[g] = f ? (int)((const unsigned char*)m)[g] : ((const int*)m)[g];
}

// ---------------- weight prep: B^T bf16, XOR-swizzled 16B chunks ----------------
__global__ void k_prep(const float* __restrict__ Wm1, const float* __restrict__ Ws1,
                       const float* __restrict__ Wm2, const float* __restrict__ Ws2,
                       const float* __restrict__ Wp,
                       unsigned short* __restrict__ B1t, unsigned short* __restrict__ B2t,
                       unsigned short* __restrict__ Bpt) {
    int m = blockIdx.x;
    const float* S0 = (m == 0) ? Wm1 : ((m == 1) ? Wm2 : Wp);
    const float* S1 = (m == 0) ? Ws1 : ((m == 1) ? Ws2 : (Wp + 128 * DD));
    unsigned short* D = (m == 0) ? B1t : ((m == 1) ? B2t : Bpt);
    for (int idx = threadIdx.x; idx < 128 * 32; idx += 256) {
        int n = idx >> 5;
        int mm = idx & 31;
        short8 pk;
#pragma unroll
        for (int j = 0; j < 8; ++j) {
            int k = mm * 8 + j;
            float v = (k < 128) ? S0[k * DD + n] : S1[(k - 128) * DD + n];
            pk[j] = (short)f2bf(v);
        }
        int mst = mm ^ (n & 7);
        *(short8*)(D + n * 256 + mst * 8) = pk;
    }
}

// ---------------- node feature mean/var sums ----------------
__global__ __launch_bounds__(256) void k_stats(const float* __restrict__ nodes, float* stats) {
    int tid = threadIdx.x;
    int gid = blockIdx.x * 256 + tid;
    float s[8] = {0.f,0.f,0.f,0.f,0.f,0.f,0.f,0.f};
    float q[8] = {0.f,0.f,0.f,0.f,0.f,0.f,0.f,0.f};
    for (int r = gid; r < NB * NND; r += 256 * 256) {
        const float* p = nodes + (size_t)r * NFEAT;
#pragma unroll
        for (int k = 0; k < 8; ++k) { float v = p[k]; s[k] += v; q[k] += v * v; }
    }
#pragma unroll
    for (int k = 0; k < 8; ++k) {
        for (int off = 32; off; off >>= 1) {
            s[k] += __shfl_xor(s[k], off, 64);
            q[k] += __shfl_xor(q[k], off, 64);
        }
    }
    __shared__ float ls[4][16];
    int w = tid >> 6, lane = tid & 63;
    if (lane == 0) {
#pragma unroll
        for (int k = 0; k < 8; ++k) { ls[w][k] = s[k]; ls[w][8 + k] = q[k]; }
    }
    __syncthreads();
    if (tid < 16) {
        float t = ls[0][tid] + ls[1][tid] + ls[2][tid] + ls[3][tid];
        atomicAdd(stats + tid, t);
    }
}

// ---------------- h0 = relu(norm(nodes) @ W_in + b_in) -> bf16 ----------------
__global__ __launch_bounds__(256) void k_h0(const float* __restrict__ nodes, const float* __restrict__ stats,
                                            const float* __restrict__ Win, const float* __restrict__ bin,
                                            unsigned short* __restrict__ h) {
    __shared__ float sW[NFEAT * DD];
    __shared__ float sb[DD];
    __shared__ float sm[8], sr[8];
    int tid = threadIdx.x;
    for (int i = tid; i < NFEAT * DD; i += 256) sW[i] = Win[i];
    if (tid < DD) sb[tid] = bin[tid];
    if (tid < 8) {
        float inv_n = 1.f / (float)(NB * NND);
        float mean = stats[tid] * inv_n;
        float var = stats[8 + tid] * inv_n - mean * mean;
        var = fmaxf(var, 0.f);
        sm[tid] = mean;
        sr[tid] = 1.f / (sqrtf(var) + 1e-8f);
    }
    __syncthreads();
    int gid = blockIdx.x * 256 + tid;
    if (gid >= NB * NND * DD) return;
    int bn = gid >> 7, j = gid & 127;
    const float* p = nodes + (size_t)bn * NFEAT;
    float acc = sb[j];
#pragma unroll
    for (int k = 0; k < 8; ++k) acc += (p[k] - sm[k]) * sr[k] * sW[k * DD + j];
    h[gid] = f2bf(fmaxf(acc, 0.f));
}

// ---------------- degree count ----------------
__global__ void k_deg(const int* __restrict__ links, int* deg) {
    int gid = blockIdx.x * 256 + threadIdx.x;
    if (gid >= NB * NED) return;
    int b = gid / NED, e = gid % NED;
    int dst = links[b * 2 * NED + NED + e];
    atomicAdd(deg + b * NND + dst, 1);
}

// ---------------- exclusive scan of degrees (wave-shfl version) ----------------
__global__ __launch_bounds__(1024) void k_scan(const int* __restrict__ deg, int* offs, int* cursor) {
    int b = blockIdx.x;
    int tid = threadIdx.x, lane = tid & 63, wv = tid >> 6;
    __shared__ int wsum[16], wexcl[16];
    __shared__ int carry_s;
    if (tid == 0) carry_s = 0;
    __syncthreads();
    for (int c = 0; c < 20; ++c) {
        int i = c * 1024 + tid;
        int v = (i < NND) ? deg[b * NND + i] : 0;
        int x = v;
#pragma unroll
        for (int d = 1; d < 64; d <<= 1) {
            int t = __shfl_up(x, d, 64);
            if (lane >= d) x += t;
        }
        if (lane == 63) wsum[wv] = x;
        __syncthreads();
        if (wv == 0) {
            int s = (lane < 16) ? wsum[lane] : 0;
#pragma unroll
            for (int d = 1; d < 16; d <<= 1) {
                int t = __shfl_up(s, d, 64);
                if (lane >= d) s += t;
            }
            if (lane < 16) wexcl[lane] = s - wsum[lane];
        }
        __syncthreads();
        int carry = carry_s;
        int excl = carry + wexcl[wv] + (x - v);
        if (i < NND) {
            offs[b * (NND + 1) + i] = excl;
            cursor[b * NND + i] = excl;
        }
        __syncthreads();
        if (tid == 0) carry_s = carry + wexcl[15] + wsum[15];
        __syncthreads();
    }
    if (tid == 0) offs[b * (NND + 1) + NND] = carry_s;
}

// ---------------- CSR fill ----------------
__global__ void k_fill(const int* __restrict__ links, int* cursor, int* csr) {
    int gid = blockIdx.x * 256 + threadIdx.x;
    if (gid >= NB * NED) return;
    int b = gid / NED, e = gid % NED;
    int src = links[b * 2 * NED + e];
    int dst = links[b * 2 * NED + NED + e];
    int p = atomicAdd(cursor + b * NND + dst, 1);
    csr[(size_t)b * NED + p] = src;
}

// ---------------- agg[n] = sum_{src->n} h[src]  (wave/node, 4 rows x 16B per iter) ----------------
__global__ __launch_bounds__(256) void k_gather(const unsigned short* __restrict__ h, const int* __restrict__ offs,
                                                const int* __restrict__ csr, unsigned short* __restrict__ agg) {
    int wid = (blockIdx.x * 256 + threadIdx.x) >> 6;
    int lane = threadIdx.x & 63;
    if (wid >= NB * NND) return;
    int b = wid / NND, n = wid % NND;
    int off0 = offs[b * (NND + 1) + n];
    int off1 = offs[b * (NND + 1) + n + 1];
    int g = lane >> 4, c = lane & 15;
    float acc[8] = {0.f,0.f,0.f,0.f,0.f,0.f,0.f,0.f};
    const uint4* hb = (const uint4*)(h + (size_t)b * NND * DD);  // 16 chunks per row
    const int* cs = csr + (size_t)b * NED;
    for (int base = off0; base < off1; base += 64) {
        int cnt = min(64, off1 - base);
        int idx = (lane < cnt) ? cs[base + lane] : 0;
        int ng = (cnt + 3) >> 2;
        for (int j = 0; j < ng; ++j) {
            int q = j * 4 + g;
            int srcn = __shfl(idx, q, 64);
            if (q < cnt) {
                uint4 v = hb[srcn * 16 + c];
                float f[8];
                unpack8(v, f);
#pragma unroll
                for (int k = 0; k < 8; ++k) acc[k] += f[k];
            }
        }
    }
#pragma unroll
    for (int k = 0; k < 8; ++k) {
        acc[k] += __shfl_xor(acc[k], 16, 64);
        acc[k] += __shfl_xor(acc[k], 32, 64);
    }
    if (lane < 16) {
        uint4 r;
        r.x = ((unsigned)f2bf(acc[1]) << 16) | (unsigned)f2bf(acc[0]);
        r.y = ((unsigned)f2bf(acc[3]) << 16) | (unsigned)f2bf(acc[2]);
        r.z = ((unsigned)f2bf(acc[5]) << 16) | (unsigned)f2bf(acc[4]);
        r.w = ((unsigned)f2bf(acc[7]) << 16) | (unsigned)f2bf(acc[6]);
        ((uint4*)(agg + (size_t)wid * DD))[c] = r;
    }
}

// ---------------- MFMA: h_new = relu([agg,h] @ Bt + bias) -> bf16 ----------------
__global__ __launch_bounds__(256) void k_mp_mfma(const unsigned short* __restrict__ Xa,
                                                 const unsigned short* __restrict__ Xh,
                                                 const unsigned short* __restrict__ Bt,
                                                 const float* __restrict__ bias,
                                                 unsigned short* __restrict__ Out) {
    __shared__ unsigned short sB[128 * 256];
    {
        const uint4* s4 = (const uint4*)Bt;
        uint4* d4 = (uint4*)sB;
        for (int i = threadIdx.x; i < 4096; i += 256) d4[i] = s4[i];
    }
    __syncthreads();
    int wave = threadIdx.x >> 6, lane = threadIdx.x & 63;
    int row0 = blockIdx.x * 256 + wave * 64;
    int arow = lane & 15, kgrp = lane >> 4;
    f32x4 acc[4][8];
#pragma unroll
    for (int s = 0; s < 4; ++s)
#pragma unroll
        for (int c = 0; c < 8; ++c) acc[s][c] = (f32x4){0.f, 0.f, 0.f, 0.f};
    const unsigned short* aptr[4];
    const unsigned short* hptr[4];
#pragma unroll
    for (int s = 0; s < 4; ++s) {
        int r = row0 + s * 16 + arow;
        int rr = (r < MROWS) ? r : (MROWS - 1);
        aptr[s] = Xa + (size_t)rr * DD + kgrp * 8;
        hptr[s] = Xh + (size_t)rr * DD + kgrp * 8;
    }
#pragma unroll
    for (int ks = 0; ks < 8; ++ks) {
        short8 a[4];
#pragma unroll
        for (int s = 0; s < 4; ++s)
            a[s] = (ks < 4) ? *(const short8*)(aptr[s] + ks * 32)
                            : *(const short8*)(hptr[s] + (ks - 4) * 32);
#pragma unroll
        for (int c = 0; c < 8; ++c) {
            int n = c * 16 + arow;
            int mst = (ks * 4 + kgrp) ^ (n & 7);
            short8 bfr = *(const short8*)(sB + n * 256 + mst * 8);
#pragma unroll
            for (int s = 0; s < 4; ++s)
                acc[s][c] = __builtin_amdgcn_mfma_f32_16x16x32_bf16(a[s], bfr, acc[s][c], 0, 0, 0);
        }
    }
    float bcol[8];
#pragma unroll
    for (int c = 0; c < 8; ++c) bcol[c] = bias[c * 16 + arow];
#pragma unroll
    for (int s = 0; s < 4; ++s) {
#pragma unroll
        for (int j = 0; j < 4; ++j) {
            int r = row0 + s * 16 + kgrp * 4 + j;
            if (r < MROWS) {
                unsigned short* orow = Out + (size_t)r * DD;
#pragma unroll
                for (int c = 0; c < 8; ++c) {
                    float v = fmaxf(acc[s][c][j] + bcol[c], 0.f);
                    orow[c * 16 + arow] = f2bf(v);
                }
            }
        }
    }
}

// ---------------- a = relu(norm(ad) @ W_ad + b_ad) (fp32 + bf16 copies) ----------------
__global__ __launch_bounds__(512) void k_ad(const float* __restrict__ ad, const float* __restrict__ Wad,
                                            const float* __restrict__ bad, float* __restrict__ av,
                                            unsigned short* __restrict__ av_bf) {
    __shared__ float sn[NB * ADF];
    int tid = threadIdx.x;
    if (tid < ADF) {
        float m = 0.f;
        for (int b = 0; b < NB; ++b) m += ad[b * ADF + tid];
        m *= 0.25f;
        float v = 0.f;
        for (int b = 0; b < NB; ++b) { float d = ad[b * ADF + tid] - m; v += d * d; }
        v *= 0.25f;
        float r = 1.f / (sqrtf(v) + 1e-8f);
        for (int b = 0; b < NB; ++b) sn[b * ADF + tid] = (ad[b * ADF + tid] - m) * r;
    }
    __syncthreads();
    int b = tid >> 7, j = tid & 127;
    float acc = bad[j];
#pragma unroll
    for (int k = 0; k < 8; ++k) acc += sn[b * ADF + k] * Wad[k * DD + j];
    float rl = fmaxf(acc, 0.f);
    av[tid] = rl;
    av_bf[tid] = f2bf(rl);
}

// ---------------- MFMA pair+dot: logits = mask ? relu([h,a]@Wp+bp).wout : NEGINF ----------------
__global__ __launch_bounds__(256) void k_pair_mfma(const unsigned short* __restrict__ Xh,
                                                   const unsigned short* __restrict__ Abf,
                                                   const unsigned short* __restrict__ Bt,
                                                   const float* __restrict__ bp,
                                                   const float* __restrict__ wout,
                                                   const int* __restrict__ mc,
                                                   float* __restrict__ logits) {
    __shared__ unsigned short sB[128 * 256];
    {
        const uint4* s4 = (const uint4*)Bt;
        uint4* d4 = (uint4*)sB;
        for (int i = threadIdx.x; i < 4096; i += 256) d4[i] = s4[i];
    }
    __syncthreads();
    int wave = threadIdx.x >> 6, lane = threadIdx.x & 63;
    int row0 = blockIdx.x * 256 + wave * 64;
    int arow = lane & 15, kgrp = lane >> 4;
    f32x4 acc[4][8];
#pragma unroll
    for (int s = 0; s < 4; ++s)
#pragma unroll
        for (int c = 0; c < 8; ++c) acc[s][c] = (f32x4){0.f, 0.f, 0.f, 0.f};
    const unsigned short* hptr[4];
    const unsigned short* aptr[4];
#pragma unroll
    for (int s = 0; s < 4; ++s) {
        int r = row0 + s * 16 + arow;
        int rr = (r < MROWS) ? r : (MROWS - 1);
        hptr[s] = Xh + (size_t)rr * DD + kgrp * 8;
        aptr[s] = Abf + (size_t)(rr / NND) * DD + kgrp * 8;
    }
#pragma unroll
    for (int ks = 0; ks < 8; ++ks) {
        short8 a[4];
#pragma unroll
        for (int s = 0; s < 4; ++s)
            a[s] = (ks < 4) ? *(const short8*)(hptr[s] + ks * 32)
                            : *(const short8*)(aptr[s] + (ks - 4) * 32);
#pragma unroll
        for (int c = 0; c < 8; ++c) {
            int n = c * 16 + arow;
            int mst = (ks * 4 + kgrp) ^ (n & 7);
            short8 bfr = *(const short8*)(sB + n * 256 + mst * 8);
#pragma unroll
            for (int s = 0; s < 4; ++s)
                acc[s][c] = __builtin_amdgcn_mfma_f32_16x16x32_bf16(a[s], bfr, acc[s][c], 0, 0, 0);
        }
    }
    float bpc[8], wc[8];
#pragma unroll
    for (int c = 0; c < 8; ++c) {
        int col = c * 16 + arow;
        bpc[c] = bp[col];
        wc[c] = wout[col];
    }
#pragma unroll
    for (int s = 0; s < 4; ++s) {
#pragma unroll
        for (int j = 0; j < 4; ++j) {
            float v = 0.f;
#pragma unroll
            for (int c = 0; c < 8; ++c)
                v += fmaxf(acc[s][c][j] + bpc[c], 0.f) * wc[c];
            v += __shfl_xor(v, 1, 64);
            v += __shfl_xor(v, 2, 64);
            v += __shfl_xor(v, 4, 64);
            v += __shfl_xor(v, 8, 64);
            int r = row0 + s * 16 + kgrp * 4 + j;
            if (arow == 0 && r < MROWS)
                logits[r] = mc[r] ? v : NEGINF;
        }
    }
}

// ---------------- softmax max ----------------
__global__ __launch_bounds__(256) void k_max(const float* __restrict__ logits, unsigned* mtrans) {
    int b = blockIdx.x >> 6, chunk = blockIdx.x & 63, tid = threadIdx.x;
    float m = -3.0e38f;
    for (int i = chunk * 256 + tid; i < NND; i += 64 * 256) m = fmaxf(m, logits[b * NND + i]);
    for (int off = 32; off; off >>= 1) m = fmaxf(m, __shfl_xor(m, off, 64));
    __shared__ float lm[4];
    if ((tid & 63) == 0) lm[tid >> 6] = m;
    __syncthreads();
    if (tid == 0) {
        m = fmaxf(fmaxf(lm[0], lm[1]), fmaxf(lm[2], lm[3]));
        atomicMax(mtrans + b, ftrans(m));
    }
}

// ---------------- fused sumexp + context (4 rows x 16B per wave-iter) ----------------
#define CTX_CH 128
#define CTX_RPB ((NND + CTX_CH - 1) / CTX_CH)
__global__ __launch_bounds__(256) void k_ctxsum(const float* __restrict__ logits, const unsigned short* __restrict__ h,
                                                const unsigned* __restrict__ mtrans, float* S, float* ctx) {
    int b = blockIdx.x >> 7, chunk = blockIdx.x & (CTX_CH - 1);
    int rowstart = chunk * CTX_RPB;
    int rowend = min(rowstart + CTX_RPB, NND);
    int wave = threadIdx.x >> 6, lane = threadIdx.x & 63;
    int g = lane >> 4, c = lane & 15;
    float m = finv(mtrans[b]);
    float acc[8] = {0.f,0.f,0.f,0.f,0.f,0.f,0.f,0.f};
    float ws = 0.f;
    const uint4* hb = (const uint4*)(h + (size_t)b * NND * DD);
    const float* lg = logits + b * NND;
    for (int r0 = rowstart + wave * 4; r0 < rowend; r0 += 16) {
        int row = r0 + g;
        if (row < rowend) {
            float w = expf(lg[row] - m);
            ws += w;
            uint4 v = hb[row * 16 + c];
            float f[8];
            unpack8(v, f);
#pragma unroll
            for (int k = 0; k < 8; ++k) acc[k] += w * f[k];
        }
    }
#pragma unroll
    for (int k = 0; k < 8; ++k) {
        acc[k] += __shfl_xor(acc[k], 16, 64);
        acc[k] += __shfl_xor(acc[k], 32, 64);
    }
    ws += __shfl_xor(ws, 16, 64);
    ws += __shfl_xor(ws, 32, 64);
    // ws now summed over g but duplicated across the 16 c-lanes? No: each (g,c) lane
    // accumulated w once per row (rows distinct per g), so after g-reduction every
    // lane holds the wave's true row-sum. Take it from lane 0.
    __shared__ float sctx[4][128];
    __shared__ float sws[4];
    if (lane < 16) {
#pragma unroll
        for (int k = 0; k < 8; ++k) sctx[wave][lane * 8 + k] = acc[k];
    }
    if (lane == 0) sws[wave] = ws;
    __syncthreads();
    int tid = threadIdx.x;
    if (tid < 128) {
        float t = sctx[0][tid] + sctx[1][tid] + sctx[2][tid] + sctx[3][tid];
        atomicAdd(ctx + b * DD + tid, t);
    }
    if (tid == 0) atomicAdd(S + b, sws[0] + sws[1] + sws[2] + sws[3]);
}

// ---------------- log_probs out ----------------
__global__ __launch_bounds__(256) void k_final(const float* __restrict__ logits, const unsigned* __restrict__ mtrans,
                                               const float* __restrict__ S, float* __restrict__ out) {
    int g = blockIdx.x * 256 + threadIdx.x;
    if (g >= NB * NND) return;
    int b = g / NND;
    out[g] = logits[g] - finv(mtrans[b]) - logf(S[b]);
}

// ---------------- value head ----------------
__global__ __launch_bounds__(512) void k_value(const float* __restrict__ ctx, const float* __restrict__ S,
                                               const float* __restrict__ av, const float* __restrict__ Wv,
                                               const float* __restrict__ bv, const float* __restrict__ wvo,
                                               float* __restrict__ out) {
    int tid = threadIdx.x, b = tid >> 7, j = tid & 127;
    float sb = S[b];
    float s1 = 0.f, s2 = 0.f;
    for (int k = 0; k < 128; ++k) s1 += ctx[b * DD + k] * Wv[k * DD + j];
    for (int k = 0; k < 128; ++k) s2 += av[b * DD + k] * Wv[(128 + k) * DD + j];
    float acc = bv[j] + s1 / sb + s2;
    float p = fmaxf(acc, 0.f) * wvo[j];
    __shared__ float red[512];
    red[tid] = p;
    __syncthreads();
    for (int off = 64; off; off >>= 1) {
        if (j < off) red[tid] += red[tid + off];
        __syncthreads();
    }
    if (j == 0) out[NB * NND + b] = red[tid];
}

extern "C" void kernel_launch(void* const* d_in, const int* in_sizes, int n_in,
                              void* d_out, int out_size, void* d_ws, size_t ws_size,
                              hipStream_t stream) {
    const float* nodes = (const float*)d_in[0];
    const int* links = (const int*)d_in[1];
    const void* mask = d_in[2];
    const float* ad = (const float*)d_in[3];
    const float* Win = (const float*)d_in[4];
    const float* bin = (const float*)d_in[5];
    const float* Wm1 = (const float*)d_in[6];
    const float* Ws1 = (const float*)d_in[7];
    const float* b1 = (const float*)d_in[8];
    const float* Wm2 = (const float*)d_in[9];
    const float* Ws2 = (const float*)d_in[10];
    const float* b2 = (const float*)d_in[11];
    const float* Wad = (const float*)d_in[12];
    const float* bad = (const float*)d_in[13];
    const float* Wp = (const float*)d_in[14];
    const float* bp = (const float*)d_in[15];
    const float* wout = (const float*)d_in[16];
    const float* Wv = (const float*)d_in[17];
    const float* bv = (const float*)d_in[18];
    const float* wvo = (const float*)d_in[19];
    float* out = (float*)d_out;

    unsigned short* hA = (unsigned short*)d_ws;     // h0/h1/h2
    unsigned short* hB = hA + 10240000;             // agg
    unsigned short* B1t = hB + 10240000;
    unsigned short* B2t = B1t + 32768;
    unsigned short* Bpt = B2t + 32768;
    unsigned short* a_bf = Bpt + 32768;
    float* logits = (float*)(a_bf + 512);
    float* stats = logits + 80000;
    float* a_vec = stats + 64;
    float* Sexp = a_vec + 512;
    float* ctxb = Sexp + 64;
    unsigned* mtrans = (unsigned*)(ctxb + 512);
    int* deg = (int*)(mtrans + 64);
    int* offs = deg + 80000;
    int* cursor = offs + 80064;
    int* csr = cursor + 80000;
    int* mc = csr + 1280000;
    int* flag = mc + 80000;

    k_init<<<313, 256, 0, stream>>>(stats, deg, mtrans, Sexp, ctxb);
    k_flag<<<1, 256, 0, stream>>>((const unsigned char*)mask, flag);
    k_maskc<<<313, 256, 0, stream>>>(mask, flag, mc);
    k_prep<<<3, 256, 0, stream>>>(Wm1, Ws1, Wm2, Ws2, Wp, B1t, B2t, Bpt);
    k_stats<<<256, 256, 0, stream>>>(nodes, stats);
    k_h0<<<40000, 256, 0, stream>>>(nodes, stats, Win, bin, hA);
    k_deg<<<5000, 256, 0, stream>>>(links, deg);
    k_scan<<<4, 1024, 0, stream>>>(deg, offs, cursor);
    k_fill<<<5000, 256, 0, stream>>>(links, cursor, csr);

    k_gather<<<20000, 256, 0, stream>>>(hA, offs, csr, hB);
    k_mp_mfma<<<313, 256, 0, stream>>>(hB, hA, B1t, b1, hA);
    k_gather<<<20000, 256, 0, stream>>>(hA, offs, csr, hB);
    k_mp_mfma<<<313, 256, 0, stream>>>(hB, hA, B2t, b2, hA);

    k_ad<<<1, 512, 0, stream>>>(ad, Wad, bad, a_vec, a_bf);
    k_pair_mfma<<<313, 256, 0, stream>>>(hA, a_bf, Bpt, bp, wout, mc, logits);

    k_max<<<256, 256, 0, stream>>>(logits, mtrans);
    k_ctxsum<<<NB * CTX_CH, 256, 0, stream>>>(logits, hA, mtrans, Sexp, ctxb);
    k_final<<<313, 256, 0, stream>>>(logits, mtrans, Sexp, out);
    k_value<<<1, 512, 0, stream>>>(ctxb, Sexp, a_vec, Wv, bv, wvo, out);
}

// Round 5
// 377.422 us; speedup vs baseline: 5.9143x; 1.0551x over previous
//
#include <hip/hip_runtime.h>
#include <hip/hip_bf16.h>
#include <math.h>

#define NND 20000
#define NED 320000
#define NB 4
#define NFEAT 8
#define ADF 8
#define DD 128
#define MROWS (NB * NND)
#define NEGINF -1000000000.0f

typedef __attribute__((ext_vector_type(8))) short short8;
typedef __attribute__((ext_vector_type(4))) float f32x4;

__device__ __forceinline__ unsigned ftrans(float f) {
    unsigned u = __float_as_uint(f);
    return (u & 0x80000000u) ? ~u : (u | 0x80000000u);
}
__device__ __forceinline__ float finv(unsigned t) {
    unsigned u = (t & 0x80000000u) ? (t & 0x7fffffffu) : ~t;
    return __uint_as_float(u);
}
__device__ __forceinline__ unsigned short f2bf(float f) {  // RNE, finite inputs
    unsigned u = __float_as_uint(f);
    unsigned r = u + 0x7fffu + ((u >> 16) & 1u);
    return (unsigned short)(r >> 16);
}
__device__ __forceinline__ float bf2f(unsigned short b) {
    return __uint_as_float(((unsigned)b) << 16);
}
__device__ __forceinline__ void unpack8(uint4 v, float* f) {
    f[0] = __uint_as_float(v.x << 16); f[1] = __uint_as_float(v.x & 0xffff0000u);
    f[2] = __uint_as_float(v.y << 16); f[3] = __uint_as_float(v.y & 0xffff0000u);
    f[4] = __uint_as_float(v.z << 16); f[5] = __uint_as_float(v.z & 0xffff0000u);
    f[6] = __uint_as_float(v.w << 16); f[7] = __uint_as_float(v.w & 0xffff0000u);
}

// ---------------- init scratch accumulators ----------------
__global__ void k_init(float* stats, int* deg, unsigned* mtrans, float* S, float* ctx) {
    int i = blockIdx.x * 256 + threadIdx.x;
    if (i < 16) stats[i] = 0.f;
    if (i < NB * NND) deg[i] = 0;
    if (i < NB) { mtrans[i] = 0u; S[i] = 0.f; }
    if (i < NB * DD) ctx[i] = 0.f;
}

// ---------------- mask dtype detection (bool/uint8 vs int32) ----------------
__global__ void k_flag(const unsigned char* __restrict__ m, int* flag) {
    __shared__ int any;
    if (threadIdx.x == 0) any = 0;
    __syncthreads();
    int found = 0;
    for (int p = threadIdx.x; p < 4096; p += 256)
        if ((p & 3) && m[p]) found = 1;
    if (found) atomicOr(&any, 1);
    __syncthreads();
    if (threadIdx.x == 0) *flag = any;
}

__global__ void k_maskc(const void* __restrict__ m, const int* __restrict__ flag, int* __restrict__ mc) {
    int g = blockIdx.x * 256 + threadIdx.x;
    if (g >= NB * NND) return;
    int f = *flag;
    mc[g] = f ? (int)((const unsigned char*)m)[g] : ((const int*)m)[g];
}

// ---------------- weight prep: B^T bf16, XOR-swizzled 16B chunks ----------------
__global__ void k_prep(const float* __restrict__ Wm1, const float* __restrict__ Ws1,
                       const float* __restrict__ Wm2, const float* __restrict__ Ws2,
                       const float* __restrict__ Wp,
                       unsigned short* __restrict__ B1t, unsigned short* __restrict__ B2t,
                       unsigned short* __restrict__ Bpt) {
    int m = blockIdx.x;
    const float* S0 = (m == 0) ? Wm1 : ((m == 1) ? Wm2 : Wp);
    const float* S1 = (m == 0) ? Ws1 : ((m == 1) ? Ws2 : (Wp + 128 * DD));
    unsigned short* D = (m == 0) ? B1t : ((m == 1) ? B2t : Bpt);
    for (int idx = threadIdx.x; idx < 128 * 32; idx += 256) {
        int n = idx >> 5;
        int mm = idx & 31;
        short8 pk;
#pragma unroll
        for (int j = 0; j < 8; ++j) {
            int k = mm * 8 + j;
            float v = (k < 128) ? S0[k * DD + n] : S1[(k - 128) * DD + n];
            pk[j] = (short)f2bf(v);
        }
        int mst = mm ^ (n & 7);
        *(short8*)(D + n * 256 + mst * 8) = pk;
    }
}

// ---------------- node feature mean/var sums ----------------
__global__ __launch_bounds__(256) void k_stats(const float* __restrict__ nodes, float* stats) {
    int tid = threadIdx.x;
    int gid = blockIdx.x * 256 + tid;
    float s[8] = {0.f,0.f,0.f,0.f,0.f,0.f,0.f,0.f};
    float q[8] = {0.f,0.f,0.f,0.f,0.f,0.f,0.f,0.f};
    for (int r = gid; r < NB * NND; r += 256 * 256) {
        const float* p = nodes + (size_t)r * NFEAT;
#pragma unroll
        for (int k = 0; k < 8; ++k) { float v = p[k]; s[k] += v; q[k] += v * v; }
    }
#pragma unroll
    for (int k = 0; k < 8; ++k) {
        for (int off = 32; off; off >>= 1) {
            s[k] += __shfl_xor(s[k], off, 64);
            q[k] += __shfl_xor(q[k], off, 64);
        }
    }
    __shared__ float ls[4][16];
    int w = tid >> 6, lane = tid & 63;
    if (lane == 0) {
#pragma unroll
        for (int k = 0; k < 8; ++k) { ls[w][k] = s[k]; ls[w][8 + k] = q[k]; }
    }
    __syncthreads();
    if (tid < 16) {
        float t = ls[0][tid] + ls[1][tid] + ls[2][tid] + ls[3][tid];
        atomicAdd(stats + tid, t);
    }
}

// ---------------- h0 = relu(norm(nodes) @ W_in + b_in) -> bf16 ----------------
__global__ __launch_bounds__(256) void k_h0(const float* __restrict__ nodes, const float* __restrict__ stats,
                                            const float* __restrict__ Win, const float* __restrict__ bin,
                                            unsigned short* __restrict__ h) {
    __shared__ float sW[NFEAT * DD];
    __shared__ float sb[DD];
    __shared__ float sm[8], sr[8];
    int tid = threadIdx.x;
    for (int i = tid; i < NFEAT * DD; i += 256) sW[i] = Win[i];
    if (tid < DD) sb[tid] = bin[tid];
    if (tid < 8) {
        float inv_n = 1.f / (float)(NB * NND);
        float mean = stats[tid] * inv_n;
        float var = stats[8 + tid] * inv_n - mean * mean;
        var = fmaxf(var, 0.f);
        sm[tid] = mean;
        sr[tid] = 1.f / (sqrtf(var) + 1e-8f);
    }
    __syncthreads();
    int gid = blockIdx.x * 256 + tid;
    if (gid >= NB * NND * DD) return;
    int bn = gid >> 7, j = gid & 127;
    const float* p = nodes + (size_t)bn * NFEAT;
    float acc = sb[j];
#pragma unroll
    for (int k = 0; k < 8; ++k) acc += (p[k] - sm[k]) * sr[k] * sW[k * DD + j];
    h[gid] = f2bf(fmaxf(acc, 0.f));
}

// ---------------- degree count ----------------
__global__ void k_deg(const int* __restrict__ links, int* deg) {
    int gid = blockIdx.x * 256 + threadIdx.x;
    if (gid >= NB * NED) return;
    int b = gid / NED, e = gid % NED;
    int dst = links[b * 2 * NED + NED + e];
    atomicAdd(deg + b * NND + dst, 1);
}

// ---------------- exclusive scan of degrees (wave-shfl version) ----------------
__global__ __launch_bounds__(1024) void k_scan(const int* __restrict__ deg, int* offs, int* cursor) {
    int b = blockIdx.x;
    int tid = threadIdx.x, lane = tid & 63, wv = tid >> 6;
    __shared__ int wsum[16], wexcl[16];
    __shared__ int carry_s;
    if (tid == 0) carry_s = 0;
    __syncthreads();
    for (int c = 0; c < 20; ++c) {
        int i = c * 1024 + tid;
        int v = (i < NND) ? deg[b * NND + i] : 0;
        int x = v;
#pragma unroll
        for (int d = 1; d < 64; d <<= 1) {
            int t = __shfl_up(x, d, 64);
            if (lane >= d) x += t;
        }
        if (lane == 63) wsum[wv] = x;
        __syncthreads();
        if (wv == 0) {
            int s = (lane < 16) ? wsum[lane] : 0;
#pragma unroll
            for (int d = 1; d < 16; d <<= 1) {
                int t = __shfl_up(s, d, 64);
                if (lane >= d) s += t;
            }
            if (lane < 16) wexcl[lane] = s - wsum[lane];
        }
        __syncthreads();
        int carry = carry_s;
        int excl = carry + wexcl[wv] + (x - v);
        if (i < NND) {
            offs[b * (NND + 1) + i] = excl;
            cursor[b * NND + i] = excl;
        }
        __syncthreads();
        if (tid == 0) carry_s = carry + wexcl[15] + wsum[15];
        __syncthreads();
    }
    if (tid == 0) offs[b * (NND + 1) + NND] = carry_s;
}

// ---------------- CSR fill, XCD-range-filtered ----------------
// dst space split into 8 ranges; range == blockIdx%8 -> lands on one XCD
// (dispatch round-robin). All cursor/csr lines for a range are then written
// by a single XCD's L2 -> one writeback instead of ~14 partial ones.
#define FILL_CHUNK 64
__global__ __launch_bounds__(256) void k_fill(const int* __restrict__ links, int* cursor, int* csr) {
    int bid = blockIdx.x;
    int rng = bid & 7;
    int rest = bid >> 3;
    int b = rest & 3;
    int chunk = rest >> 2;
    const int lo = rng * (NND / 8), hi = lo + (NND / 8);
    const int epc = NED / FILL_CHUNK;
    const int e0 = chunk * epc;
    const int* dstp = links + b * 2 * NED + NED;
    const int* srcp = links + b * 2 * NED;
    int* cur = cursor + b * NND;
    int* cs = csr + (size_t)b * NED;
    for (int e = e0 + threadIdx.x; e < e0 + epc; e += 256) {
        int d = dstp[e];
        if (d >= lo && d < hi) {
            int p = atomicAdd(cur + d, 1);
            cs[p] = srcp[e];
        }
    }
}

// ---------------- agg[n] = sum_{src->n} h[src]  (wave/node, 4 rows x 16B per iter) ----------------
__global__ __launch_bounds__(256) void k_gather(const unsigned short* __restrict__ h, const int* __restrict__ offs,
                                                const int* __restrict__ csr, unsigned short* __restrict__ agg) {
    int wid = (blockIdx.x * 256 + threadIdx.x) >> 6;
    int lane = threadIdx.x & 63;
    if (wid >= NB * NND) return;
    int b = wid / NND, n = wid % NND;
    int off0 = offs[b * (NND + 1) + n];
    int off1 = offs[b * (NND + 1) + n + 1];
    int g = lane >> 4, c = lane & 15;
    float acc[8] = {0.f,0.f,0.f,0.f,0.f,0.f,0.f,0.f};
    const uint4* hb = (const uint4*)(h + (size_t)b * NND * DD);
    const int* cs = csr + (size_t)b * NED;
    for (int base = off0; base < off1; base += 64) {
        int cnt = min(64, off1 - base);
        int idx = (lane < cnt) ? cs[base + lane] : 0;
        int ng = (cnt + 3) >> 2;
        for (int j = 0; j < ng; ++j) {
            int q = j * 4 + g;
            int srcn = __shfl(idx, q, 64);
            if (q < cnt) {
                uint4 v = hb[srcn * 16 + c];
                float f[8];
                unpack8(v, f);
#pragma unroll
                for (int k = 0; k < 8; ++k) acc[k] += f[k];
            }
        }
    }
#pragma unroll
    for (int k = 0; k < 8; ++k) {
        acc[k] += __shfl_xor(acc[k], 16, 64);
        acc[k] += __shfl_xor(acc[k], 32, 64);
    }
    if (lane < 16) {
        uint4 r;
        r.x = ((unsigned)f2bf(acc[1]) << 16) | (unsigned)f2bf(acc[0]);
        r.y = ((unsigned)f2bf(acc[3]) << 16) | (unsigned)f2bf(acc[2]);
        r.z = ((unsigned)f2bf(acc[5]) << 16) | (unsigned)f2bf(acc[4]);
        r.w = ((unsigned)f2bf(acc[7]) << 16) | (unsigned)f2bf(acc[6]);
        ((uint4*)(agg + (size_t)wid * DD))[c] = r;
    }
}

// ---------------- MFMA: h_new = relu([agg,h] @ Bt + bias) -> bf16 ----------------
__global__ __launch_bounds__(256) void k_mp_mfma(const unsigned short* __restrict__ Xa,
                                                 const unsigned short* __restrict__ Xh,
                                                 const unsigned short* __restrict__ Bt,
                                                 const float* __restrict__ bias,
                                                 unsigned short* __restrict__ Out) {
    __shared__ unsigned short sB[128 * 256];
    {
        const uint4* s4 = (const uint4*)Bt;
        uint4* d4 = (uint4*)sB;
        for (int i = threadIdx.x; i < 4096; i += 256) d4[i] = s4[i];
    }
    __syncthreads();
    int wave = threadIdx.x >> 6, lane = threadIdx.x & 63;
    int row0 = blockIdx.x * 256 + wave * 64;
    int arow = lane & 15, kgrp = lane >> 4;
    f32x4 acc[4][8];
#pragma unroll
    for (int s = 0; s < 4; ++s)
#pragma unroll
        for (int c = 0; c < 8; ++c) acc[s][c] = (f32x4){0.f, 0.f, 0.f, 0.f};
    const unsigned short* aptr[4];
    const unsigned short* hptr[4];
#pragma unroll
    for (int s = 0; s < 4; ++s) {
        int r = row0 + s * 16 + arow;
        int rr = (r < MROWS) ? r : (MROWS - 1);
        aptr[s] = Xa + (size_t)rr * DD + kgrp * 8;
        hptr[s] = Xh + (size_t)rr * DD + kgrp * 8;
    }
#pragma unroll
    for (int ks = 0; ks < 8; ++ks) {
        short8 a[4];
#pragma unroll
        for (int s = 0; s < 4; ++s)
            a[s] = (ks < 4) ? *(const short8*)(aptr[s] + ks * 32)
                            : *(const short8*)(hptr[s] + (ks - 4) * 32);
#pragma unroll
        for (int c = 0; c < 8; ++c) {
            int n = c * 16 + arow;
            int mst = (ks * 4 + kgrp) ^ (n & 7);
            short8 bfr = *(const short8*)(sB + n * 256 + mst * 8);
#pragma unroll
            for (int s = 0; s < 4; ++s)
                acc[s][c] = __builtin_amdgcn_mfma_f32_16x16x32_bf16(a[s], bfr, acc[s][c], 0, 0, 0);
        }
    }
    float bcol[8];
#pragma unroll
    for (int c = 0; c < 8; ++c) bcol[c] = bias[c * 16 + arow];
#pragma unroll
    for (int s = 0; s < 4; ++s) {
#pragma unroll
        for (int j = 0; j < 4; ++j) {
            int r = row0 + s * 16 + kgrp * 4 + j;
            if (r < MROWS) {
                unsigned short* orow = Out + (size_t)r * DD;
#pragma unroll
                for (int c = 0; c < 8; ++c) {
                    float v = fmaxf(acc[s][c][j] + bcol[c], 0.f);
                    orow[c * 16 + arow] = f2bf(v);
                }
            }
        }
    }
}

// ---------------- a = relu(norm(ad) @ W_ad + b_ad) (fp32 + bf16 copies) ----------------
__global__ __launch_bounds__(512) void k_ad(const float* __restrict__ ad, const float* __restrict__ Wad,
                                            const float* __restrict__ bad, float* __restrict__ av,
                                            unsigned short* __restrict__ av_bf) {
    __shared__ float sn[NB * ADF];
    int tid = threadIdx.x;
    if (tid < ADF) {
        float m = 0.f;
        for (int b = 0; b < NB; ++b) m += ad[b * ADF + tid];
        m *= 0.25f;
        float v = 0.f;
        for (int b = 0; b < NB; ++b) { float d = ad[b * ADF + tid] - m; v += d * d; }
        v *= 0.25f;
        float r = 1.f / (sqrtf(v) + 1e-8f);
        for (int b = 0; b < NB; ++b) sn[b * ADF + tid] = (ad[b * ADF + tid] - m) * r;
    }
    __syncthreads();
    int b = tid >> 7, j = tid & 127;
    float acc = bad[j];
#pragma unroll
    for (int k = 0; k < 8; ++k) acc += sn[b * ADF + k] * Wad[k * DD + j];
    float rl = fmaxf(acc, 0.f);
    av[tid] = rl;
    av_bf[tid] = f2bf(rl);
}

// ---------------- MFMA pair+dot: logits + fused batch-max ----------------
__global__ __launch_bounds__(256) void k_pair_mfma(const unsigned short* __restrict__ Xh,
                                                   const unsigned short* __restrict__ Abf,
                                                   const unsigned short* __restrict__ Bt,
                                                   const float* __restrict__ bp,
                                                   const float* __restrict__ wout,
                                                   const int* __restrict__ mc,
                                                   float* __restrict__ logits,
                                                   unsigned* __restrict__ mtrans) {
    __shared__ unsigned short sB[128 * 256];
    __shared__ unsigned smax[NB];
    {
        const uint4* s4 = (const uint4*)Bt;
        uint4* d4 = (uint4*)sB;
        for (int i = threadIdx.x; i < 4096; i += 256) d4[i] = s4[i];
        if (threadIdx.x < NB) smax[threadIdx.x] = 0u;
    }
    __syncthreads();
    int wave = threadIdx.x >> 6, lane = threadIdx.x & 63;
    int row0 = blockIdx.x * 256 + wave * 64;
    int arow = lane & 15, kgrp = lane >> 4;
    f32x4 acc[4][8];
#pragma unroll
    for (int s = 0; s < 4; ++s)
#pragma unroll
        for (int c = 0; c < 8; ++c) acc[s][c] = (f32x4){0.f, 0.f, 0.f, 0.f};
    const unsigned short* hptr[4];
    const unsigned short* aptr[4];
#pragma unroll
    for (int s = 0; s < 4; ++s) {
        int r = row0 + s * 16 + arow;
        int rr = (r < MROWS) ? r : (MROWS - 1);
        hptr[s] = Xh + (size_t)rr * DD + kgrp * 8;
        aptr[s] = Abf + (size_t)(rr / NND) * DD + kgrp * 8;
    }
#pragma unroll
    for (int ks = 0; ks < 8; ++ks) {
        short8 a[4];
#pragma unroll
        for (int s = 0; s < 4; ++s)
            a[s] = (ks < 4) ? *(const short8*)(hptr[s] + ks * 32)
                            : *(const short8*)(aptr[s] + (ks - 4) * 32);
#pragma unroll
        for (int c = 0; c < 8; ++c) {
            int n = c * 16 + arow;
            int mst = (ks * 4 + kgrp) ^ (n & 7);
            short8 bfr = *(const short8*)(sB + n * 256 + mst * 8);
#pragma unroll
            for (int s = 0; s < 4; ++s)
                acc[s][c] = __builtin_amdgcn_mfma_f32_16x16x32_bf16(a[s], bfr, acc[s][c], 0, 0, 0);
        }
    }
    float bpc[8], wc[8];
#pragma unroll
    for (int c = 0; c < 8; ++c) {
        int col = c * 16 + arow;
        bpc[c] = bp[col];
        wc[c] = wout[col];
    }
#pragma unroll
    for (int s = 0; s < 4; ++s) {
#pragma unroll
        for (int j = 0; j < 4; ++j) {
            float v = 0.f;
#pragma unroll
            for (int c = 0; c < 8; ++c)
                v += fmaxf(acc[s][c][j] + bpc[c], 0.f) * wc[c];
            v += __shfl_xor(v, 1, 64);
            v += __shfl_xor(v, 2, 64);
            v += __shfl_xor(v, 4, 64);
            v += __shfl_xor(v, 8, 64);
            int r = row0 + s * 16 + kgrp * 4 + j;
            if (arow == 0 && r < MROWS) {
                float lv = mc[r] ? v : NEGINF;
                logits[r] = lv;
                atomicMax(&smax[r / NND], ftrans(lv));
            }
        }
    }
    __syncthreads();
    if (threadIdx.x < NB && smax[threadIdx.x] != 0u)
        atomicMax(mtrans + threadIdx.x, smax[threadIdx.x]);
}

// ---------------- fused sumexp + context (4 rows x 16B per wave-iter) ----------------
#define CTX_CH 128
#define CTX_RPB ((NND + CTX_CH - 1) / CTX_CH)
__global__ __launch_bounds__(256) void k_ctxsum(const float* __restrict__ logits, const unsigned short* __restrict__ h,
                                                const unsigned* __restrict__ mtrans, float* S, float* ctx) {
    int b = blockIdx.x >> 7, chunk = blockIdx.x & (CTX_CH - 1);
    int rowstart = chunk * CTX_RPB;
    int rowend = min(rowstart + CTX_RPB, NND);
    int wave = threadIdx.x >> 6, lane = threadIdx.x & 63;
    int g = lane >> 4, c = lane & 15;
    float m = finv(mtrans[b]);
    float acc[8] = {0.f,0.f,0.f,0.f,0.f,0.f,0.f,0.f};
    float ws = 0.f;
    const uint4* hb = (const uint4*)(h + (size_t)b * NND * DD);
    const float* lg = logits + b * NND;
    for (int r0 = rowstart + wave * 4; r0 < rowend; r0 += 16) {
        int row = r0 + g;
        if (row < rowend) {
            float w = expf(lg[row] - m);
            ws += w;
            uint4 v = hb[row * 16 + c];
            float f[8];
            unpack8(v, f);
#pragma unroll
            for (int k = 0; k < 8; ++k) acc[k] += w * f[k];
        }
    }
#pragma unroll
    for (int k = 0; k < 8; ++k) {
        acc[k] += __shfl_xor(acc[k], 16, 64);
        acc[k] += __shfl_xor(acc[k], 32, 64);
    }
    ws += __shfl_xor(ws, 16, 64);
    ws += __shfl_xor(ws, 32, 64);
    __shared__ float sctx[4][128];
    __shared__ float sws[4];
    if (lane < 16) {
#pragma unroll
        for (int k = 0; k < 8; ++k) sctx[wave][lane * 8 + k] = acc[k];
    }
    if (lane == 0) sws[wave] = ws;
    __syncthreads();
    int tid = threadIdx.x;
    if (tid < 128) {
        float t = sctx[0][tid] + sctx[1][tid] + sctx[2][tid] + sctx[3][tid];
        atomicAdd(ctx + b * DD + tid, t);
    }
    if (tid == 0) atomicAdd(S + b, sws[0] + sws[1] + sws[2] + sws[3]);
}

// ---------------- log_probs out ----------------
__global__ __launch_bounds__(256) void k_final(const float* __restrict__ logits, const unsigned* __restrict__ mtrans,
                                               const float* __restrict__ S, float* __restrict__ out) {
    int g = blockIdx.x * 256 + threadIdx.x;
    if (g >= NB * NND) return;
    int b = g / NND;
    out[g] = logits[g] - finv(mtrans[b]) - logf(S[b]);
}

// ---------------- value head ----------------
__global__ __launch_bounds__(512) void k_value(const float* __restrict__ ctx, const float* __restrict__ S,
                                               const float* __restrict__ av, const float* __restrict__ Wv,
                                               const float* __restrict__ bv, const float* __restrict__ wvo,
                                               float* __restrict__ out) {
    int tid = threadIdx.x, b = tid >> 7, j = tid & 127;
    float sb = S[b];
    float s1 = 0.f, s2 = 0.f;
    for (int k = 0; k < 128; ++k) s1 += ctx[b * DD + k] * Wv[k * DD + j];
    for (int k = 0; k < 128; ++k) s2 += av[b * DD + k] * Wv[(128 + k) * DD + j];
    float acc = bv[j] + s1 / sb + s2;
    float p = fmaxf(acc, 0.f) * wvo[j];
    __shared__ float red[512];
    red[tid] = p;
    __syncthreads();
    for (int off = 64; off; off >>= 1) {
        if (j < off) red[tid] += red[tid + off];
        __syncthreads();
    }
    if (j == 0) out[NB * NND + b] = red[tid];
}

extern "C" void kernel_launch(void* const* d_in, const int* in_sizes, int n_in,
                              void* d_out, int out_size, void* d_ws, size_t ws_size,
                              hipStream_t stream) {
    const float* nodes = (const float*)d_in[0];
    const int* links = (const int*)d_in[1];
    const void* mask = d_in[2];
    const float* ad = (const float*)d_in[3];
    const float* Win = (const float*)d_in[4];
    const float* bin = (const float*)d_in[5];
    const float* Wm1 = (const float*)d_in[6];
    const float* Ws1 = (const float*)d_in[7];
    const float* b1 = (const float*)d_in[8];
    const float* Wm2 = (const float*)d_in[9];
    const float* Ws2 = (const float*)d_in[10];
    const float* b2 = (const float*)d_in[11];
    const float* Wad = (const float*)d_in[12];
    const float* bad = (const float*)d_in[13];
    const float* Wp = (const float*)d_in[14];
    const float* bp = (const float*)d_in[15];
    const float* wout = (const float*)d_in[16];
    const float* Wv = (const float*)d_in[17];
    const float* bv = (const float*)d_in[18];
    const float* wvo = (const float*)d_in[19];
    float* out = (float*)d_out;

    unsigned short* hA = (unsigned short*)d_ws;     // h0/h1/h2
    unsigned short* hB = hA + 10240000;             // agg
    unsigned short* B1t = hB + 10240000;
    unsigned short* B2t = B1t + 32768;
    unsigned short* Bpt = B2t + 32768;
    unsigned short* a_bf = Bpt + 32768;
    float* logits = (float*)(a_bf + 512);
    float* stats = logits + 80000;
    float* a_vec = stats + 64;
    float* Sexp = a_vec + 512;
    float* ctxb = Sexp + 64;
    unsigned* mtrans = (unsigned*)(ctxb + 512);
    int* deg = (int*)(mtrans + 64);
    int* offs = deg + 80000;
    int* cursor = offs + 80064;
    int* csr = cursor + 80000;
    int* mc = csr + 1280000;
    int* flag = mc + 80000;

    k_init<<<313, 256, 0, stream>>>(stats, deg, mtrans, Sexp, ctxb);
    k_flag<<<1, 256, 0, stream>>>((const unsigned char*)mask, flag);
    k_maskc<<<313, 256, 0, stream>>>(mask, flag, mc);
    k_prep<<<3, 256, 0, stream>>>(Wm1, Ws1, Wm2, Ws2, Wp, B1t, B2t, Bpt);
    k_stats<<<256, 256, 0, stream>>>(nodes, stats);
    k_h0<<<40000, 256, 0, stream>>>(nodes, stats, Win, bin, hA);
    k_deg<<<5000, 256, 0, stream>>>(links, deg);
    k_scan<<<4, 1024, 0, stream>>>(deg, offs, cursor);
    k_fill<<<8 * NB * FILL_CHUNK, 256, 0, stream>>>(links, cursor, csr);

    k_gather<<<20000, 256, 0, stream>>>(hA, offs, csr, hB);
    k_mp_mfma<<<313, 256, 0, stream>>>(hB, hA, B1t, b1, hA);
    k_gather<<<20000, 256, 0, stream>>>(hA, offs, csr, hB);
    k_mp_mfma<<<313, 256, 0, stream>>>(hB, hA, B2t, b2, hA);

    k_ad<<<1, 512, 0, stream>>>(ad, Wad, bad, a_vec, a_bf);
    k_pair_mfma<<<313, 256, 0, stream>>>(hA, a_bf, Bpt, bp, wout, mc, logits, mtrans);

    k_ctxsum<<<NB * CTX_CH, 256, 0, stream>>>(logits, hA, mtrans, Sexp, ctxb);
    k_final<<<313, 256, 0, stream>>>(logits, mtrans, Sexp, out);
    k_value<<<1, 512, 0, stream>>>(ctxb, Sexp, a_vec, Wv, bv, wvo, out);
}

// Round 6
// 371.506 us; speedup vs baseline: 6.0085x; 1.0159x over previous
//
#include <hip/hip_runtime.h>
#include <hip/hip_bf16.h>
#include <math.h>

#define NND 20000
#define NED 320000
#define NB 4
#define NFEAT 8
#define ADF 8
#define DD 128
#define MROWS (NB * NND)
#define NEGINF -1000000000.0f

typedef __attribute__((ext_vector_type(8))) short short8;
typedef __attribute__((ext_vector_type(4))) float f32x4;

__device__ __forceinline__ unsigned ftrans(float f) {
    unsigned u = __float_as_uint(f);
    return (u & 0x80000000u) ? ~u : (u | 0x80000000u);
}
__device__ __forceinline__ float finv(unsigned t) {
    unsigned u = (t & 0x80000000u) ? (t & 0x7fffffffu) : ~t;
    return __uint_as_float(u);
}
__device__ __forceinline__ unsigned short f2bf(float f) {  // RNE, finite inputs
    unsigned u = __float_as_uint(f);
    unsigned r = u + 0x7fffu + ((u >> 16) & 1u);
    return (unsigned short)(r >> 16);
}
__device__ __forceinline__ float bf2f(unsigned short b) {
    return __uint_as_float(((unsigned)b) << 16);
}
__device__ __forceinline__ void unpack8(uint4 v, float* f) {
    f[0] = __uint_as_float(v.x << 16); f[1] = __uint_as_float(v.x & 0xffff0000u);
    f[2] = __uint_as_float(v.y << 16); f[3] = __uint_as_float(v.y & 0xffff0000u);
    f[4] = __uint_as_float(v.z << 16); f[5] = __uint_as_float(v.z & 0xffff0000u);
    f[6] = __uint_as_float(v.w << 16); f[7] = __uint_as_float(v.w & 0xffff0000u);
}

// ---------------- init scratch + mask dtype flag ----------------
__global__ __launch_bounds__(256) void k_init(float* stats, int* deg, unsigned* mtrans, float* S, float* ctx,
                                              const unsigned char* __restrict__ m, int* flag) {
    if (blockIdx.x == 313) {
        // mask dtype detection: int32 0/1 has all bytes at p%4!=0 zero.
        __shared__ int any;
        if (threadIdx.x == 0) any = 0;
        __syncthreads();
        int found = 0;
        for (int p = threadIdx.x; p < 4096; p += 256)
            if ((p & 3) && m[p]) found = 1;
        if (found) atomicOr(&any, 1);
        __syncthreads();
        if (threadIdx.x == 0) *flag = any;
        return;
    }
    int i = blockIdx.x * 256 + threadIdx.x;
    if (i < 16) stats[i] = 0.f;
    if (i < NB * NND) deg[i] = 0;
    if (i < NB) { mtrans[i] = 0u; S[i] = 0.f; }
    if (i < NB * DD) ctx[i] = 0.f;
}

// ---------------- fused setup: deg + stats + maskc + prep + ad ----------------
// blocks [0,5000): degree count; [5000,5256): node stats; [5256,5569): mask
// canonicalize; [5569,5572): weight prep; 5572: ad head.
__global__ __launch_bounds__(256) void k_setup(const int* __restrict__ links, int* deg,
                                               const float* __restrict__ nodes, float* stats,
                                               const void* __restrict__ m, const int* __restrict__ flag,
                                               int* __restrict__ mc,
                                               const float* __restrict__ Wm1, const float* __restrict__ Ws1,
                                               const float* __restrict__ Wm2, const float* __restrict__ Ws2,
                                               const float* __restrict__ Wp,
                                               unsigned short* __restrict__ B1t, unsigned short* __restrict__ B2t,
                                               unsigned short* __restrict__ Bpt,
                                               const float* __restrict__ ad, const float* __restrict__ Wad,
                                               const float* __restrict__ bad, float* __restrict__ av,
                                               unsigned short* __restrict__ av_bf) {
    int bid = blockIdx.x, tid = threadIdx.x;
    if (bid < 5000) {
        int gid = bid * 256 + tid;
        int b = gid / NED, e = gid % NED;
        int dst = __builtin_nontemporal_load(links + b * 2 * NED + NED + e);
        atomicAdd(deg + b * NND + dst, 1);
        return;
    }
    if (bid < 5256) {
        int gid = (bid - 5000) * 256 + tid;
        float s[8] = {0.f,0.f,0.f,0.f,0.f,0.f,0.f,0.f};
        float q[8] = {0.f,0.f,0.f,0.f,0.f,0.f,0.f,0.f};
        for (int r = gid; r < NB * NND; r += 256 * 256) {
            const float* p = nodes + (size_t)r * NFEAT;
#pragma unroll
            for (int k = 0; k < 8; ++k) { float v = p[k]; s[k] += v; q[k] += v * v; }
        }
#pragma unroll
        for (int k = 0; k < 8; ++k) {
            for (int off = 32; off; off >>= 1) {
                s[k] += __shfl_xor(s[k], off, 64);
                q[k] += __shfl_xor(q[k], off, 64);
            }
        }
        __shared__ float ls[4][16];
        int w = tid >> 6, lane = tid & 63;
        if (lane == 0) {
#pragma unroll
            for (int k = 0; k < 8; ++k) { ls[w][k] = s[k]; ls[w][8 + k] = q[k]; }
        }
        __syncthreads();
        if (tid < 16) {
            float t = ls[0][tid] + ls[1][tid] + ls[2][tid] + ls[3][tid];
            atomicAdd(stats + tid, t);
        }
        return;
    }
    if (bid < 5569) {
        int g = (bid - 5256) * 256 + tid;
        if (g < NB * NND) {
            int f = *flag;
            mc[g] = f ? (int)((const unsigned char*)m)[g] : ((const int*)m)[g];
        }
        return;
    }
    if (bid < 5572) {
        int mtx = bid - 5569;
        const float* S0 = (mtx == 0) ? Wm1 : ((mtx == 1) ? Wm2 : Wp);
        const float* S1 = (mtx == 0) ? Ws1 : ((mtx == 1) ? Ws2 : (Wp + 128 * DD));
        unsigned short* D = (mtx == 0) ? B1t : ((mtx == 1) ? B2t : Bpt);
        for (int idx = tid; idx < 128 * 32; idx += 256) {
            int n = idx >> 5;
            int mm = idx & 31;
            short8 pk;
#pragma unroll
            for (int j = 0; j < 8; ++j) {
                int k = mm * 8 + j;
                float v = (k < 128) ? S0[k * DD + n] : S1[(k - 128) * DD + n];
                pk[j] = (short)f2bf(v);
            }
            int mst = mm ^ (n & 7);
            *(short8*)(D + n * 256 + mst * 8) = pk;
        }
        return;
    }
    // ad head (1 block)
    __shared__ float sn[NB * ADF];
    if (tid < ADF) {
        float mm = 0.f;
        for (int b = 0; b < NB; ++b) mm += ad[b * ADF + tid];
        mm *= 0.25f;
        float v = 0.f;
        for (int b = 0; b < NB; ++b) { float d = ad[b * ADF + tid] - mm; v += d * d; }
        v *= 0.25f;
        float r = 1.f / (sqrtf(v) + 1e-8f);
        for (int b = 0; b < NB; ++b) sn[b * ADF + tid] = (ad[b * ADF + tid] - mm) * r;
    }
    __syncthreads();
    for (int t = tid; t < NB * DD; t += 256) {
        int b = t >> 7, j = t & 127;
        float acc = bad[j];
#pragma unroll
        for (int k = 0; k < 8; ++k) acc += sn[b * ADF + k] * Wad[k * DD + j];
        float rl = fmaxf(acc, 0.f);
        av[t] = rl;
        av_bf[t] = f2bf(rl);
    }
}

// ---------------- h0 = relu(norm(nodes) @ W_in + b_in) -> bf16 ----------------
__global__ __launch_bounds__(256) void k_h0(const float* __restrict__ nodes, const float* __restrict__ stats,
                                            const float* __restrict__ Win, const float* __restrict__ bin,
                                            unsigned short* __restrict__ h) {
    __shared__ float sW[NFEAT * DD];
    __shared__ float sb[DD];
    __shared__ float sm[8], sr[8];
    int tid = threadIdx.x;
    for (int i = tid; i < NFEAT * DD; i += 256) sW[i] = Win[i];
    if (tid < DD) sb[tid] = bin[tid];
    if (tid < 8) {
        float inv_n = 1.f / (float)(NB * NND);
        float mean = stats[tid] * inv_n;
        float var = stats[8 + tid] * inv_n - mean * mean;
        var = fmaxf(var, 0.f);
        sm[tid] = mean;
        sr[tid] = 1.f / (sqrtf(var) + 1e-8f);
    }
    __syncthreads();
    int gid = blockIdx.x * 256 + tid;
    if (gid >= NB * NND * DD) return;
    int bn = gid >> 7, j = gid & 127;
    const float* p = nodes + (size_t)bn * NFEAT;
    float acc = sb[j];
#pragma unroll
    for (int k = 0; k < 8; ++k) acc += (p[k] - sm[k]) * sr[k] * sW[k * DD + j];
    h[gid] = f2bf(fmaxf(acc, 0.f));
}

// ---------------- exclusive scan of degrees (wave-shfl version) ----------------
__global__ __launch_bounds__(1024) void k_scan(const int* __restrict__ deg, int* offs, int* cursor) {
    int b = blockIdx.x;
    int tid = threadIdx.x, lane = tid & 63, wv = tid >> 6;
    __shared__ int wsum[16], wexcl[16];
    __shared__ int carry_s;
    if (tid == 0) carry_s = 0;
    __syncthreads();
    for (int c = 0; c < 20; ++c) {
        int i = c * 1024 + tid;
        int v = (i < NND) ? deg[b * NND + i] : 0;
        int x = v;
#pragma unroll
        for (int d = 1; d < 64; d <<= 1) {
            int t = __shfl_up(x, d, 64);
            if (lane >= d) x += t;
        }
        if (lane == 63) wsum[wv] = x;
        __syncthreads();
        if (wv == 0) {
            int s = (lane < 16) ? wsum[lane] : 0;
#pragma unroll
            for (int d = 1; d < 16; d <<= 1) {
                int t = __shfl_up(s, d, 64);
                if (lane >= d) s += t;
            }
            if (lane < 16) wexcl[lane] = s - wsum[lane];
        }
        __syncthreads();
        int carry = carry_s;
        int excl = carry + wexcl[wv] + (x - v);
        if (i < NND) {
            offs[b * (NND + 1) + i] = excl;
            cursor[b * NND + i] = excl;
        }
        __syncthreads();
        if (tid == 0) carry_s = carry + wexcl[15] + wsum[15];
        __syncthreads();
    }
    if (tid == 0) offs[b * (NND + 1) + NND] = carry_s;
}

// ---------------- CSR fill, XCD-range-filtered + non-temporal link reads ----------------
// dst split into 8 ranges; range == blockIdx%8 lands on one XCD (dispatch
// round-robin) so each csr/cursor line is written by a single XCD. The links
// streams are read non-temporal (evict-first) so they do NOT evict the
// resident csr/cursor lines from that XCD's L2 mid-kernel.
#define FILL_CHUNK 64
__global__ __launch_bounds__(256) void k_fill(const int* __restrict__ links, int* cursor, int* csr) {
    int bid = blockIdx.x;
    int rng = bid & 7;
    int rest = bid >> 3;
    int b = rest & 3;
    int chunk = rest >> 2;
    const int lo = rng * (NND / 8), hi = lo + (NND / 8);
    const int epc = NED / FILL_CHUNK;
    const int e0 = chunk * epc;
    const int* dstp = links + b * 2 * NED + NED;
    const int* srcp = links + b * 2 * NED;
    int* cur = cursor + b * NND;
    int* cs = csr + (size_t)b * NED;
    for (int e = e0 + threadIdx.x; e < e0 + epc; e += 256) {
        int d = __builtin_nontemporal_load(dstp + e);
        if (d >= lo && d < hi) {
            int p = atomicAdd(cur + d, 1);
            cs[p] = __builtin_nontemporal_load(srcp + e);
        }
    }
}

// ---------------- agg[n] = sum_{src->n} h[src]  (wave/node, 4 rows x 16B per iter) ----------------
__global__ __launch_bounds__(256) void k_gather(const unsigned short* __restrict__ h, const int* __restrict__ offs,
                                                const int* __restrict__ csr, unsigned short* __restrict__ agg) {
    int wid = (blockIdx.x * 256 + threadIdx.x) >> 6;
    int lane = threadIdx.x & 63;
    if (wid >= NB * NND) return;
    int b = wid / NND, n = wid % NND;
    int off0 = offs[b * (NND + 1) + n];
    int off1 = offs[b * (NND + 1) + n + 1];
    int g = lane >> 4, c = lane & 15;
    float acc[8] = {0.f,0.f,0.f,0.f,0.f,0.f,0.f,0.f};
    const uint4* hb = (const uint4*)(h + (size_t)b * NND * DD);
    const int* cs = csr + (size_t)b * NED;
    for (int base = off0; base < off1; base += 64) {
        int cnt = min(64, off1 - base);
        int idx = (lane < cnt) ? cs[base + lane] : 0;
        int ng = (cnt + 3) >> 2;
        for (int j = 0; j < ng; ++j) {
            int q = j * 4 + g;
            int srcn = __shfl(idx, q, 64);
            if (q < cnt) {
                uint4 v = hb[srcn * 16 + c];
                float f[8];
                unpack8(v, f);
#pragma unroll
                for (int k = 0; k < 8; ++k) acc[k] += f[k];
            }
        }
    }
#pragma unroll
    for (int k = 0; k < 8; ++k) {
        acc[k] += __shfl_xor(acc[k], 16, 64);
        acc[k] += __shfl_xor(acc[k], 32, 64);
    }
    if (lane < 16) {
        uint4 r;
        r.x = ((unsigned)f2bf(acc[1]) << 16) | (unsigned)f2bf(acc[0]);
        r.y = ((unsigned)f2bf(acc[3]) << 16) | (unsigned)f2bf(acc[2]);
        r.z = ((unsigned)f2bf(acc[5]) << 16) | (unsigned)f2bf(acc[4]);
        r.w = ((unsigned)f2bf(acc[7]) << 16) | (unsigned)f2bf(acc[6]);
        ((uint4*)(agg + (size_t)wid * DD))[c] = r;
    }
}

// ---------------- MFMA: h_new = relu([agg,h] @ Bt + bias) -> bf16 ----------------
__global__ __launch_bounds__(256) void k_mp_mfma(const unsigned short* __restrict__ Xa,
                                                 const unsigned short* __restrict__ Xh,
                                                 const unsigned short* __restrict__ Bt,
                                                 const float* __restrict__ bias,
                                                 unsigned short* __restrict__ Out) {
    __shared__ unsigned short sB[128 * 256];
    {
        const uint4* s4 = (const uint4*)Bt;
        uint4* d4 = (uint4*)sB;
        for (int i = threadIdx.x; i < 4096; i += 256) d4[i] = s4[i];
    }
    __syncthreads();
    int wave = threadIdx.x >> 6, lane = threadIdx.x & 63;
    int row0 = blockIdx.x * 256 + wave * 64;
    int arow = lane & 15, kgrp = lane >> 4;
    f32x4 acc[4][8];
#pragma unroll
    for (int s = 0; s < 4; ++s)
#pragma unroll
        for (int c = 0; c < 8; ++c) acc[s][c] = (f32x4){0.f, 0.f, 0.f, 0.f};
    const unsigned short* aptr[4];
    const unsigned short* hptr[4];
#pragma unroll
    for (int s = 0; s < 4; ++s) {
        int r = row0 + s * 16 + arow;
        int rr = (r < MROWS) ? r : (MROWS - 1);
        aptr[s] = Xa + (size_t)rr * DD + kgrp * 8;
        hptr[s] = Xh + (size_t)rr * DD + kgrp * 8;
    }
#pragma unroll
    for (int ks = 0; ks < 8; ++ks) {
        short8 a[4];
#pragma unroll
        for (int s = 0; s < 4; ++s)
            a[s] = (ks < 4) ? *(const short8*)(aptr[s] + ks * 32)
                            : *(const short8*)(hptr[s] + (ks - 4) * 32);
#pragma unroll
        for (int c = 0; c < 8; ++c) {
            int n = c * 16 + arow;
            int mst = (ks * 4 + kgrp) ^ (n & 7);
            short8 bfr = *(const short8*)(sB + n * 256 + mst * 8);
#pragma unroll
            for (int s = 0; s < 4; ++s)
                acc[s][c] = __builtin_amdgcn_mfma_f32_16x16x32_bf16(a[s], bfr, acc[s][c], 0, 0, 0);
        }
    }
    float bcol[8];
#pragma unroll
    for (int c = 0; c < 8; ++c) bcol[c] = bias[c * 16 + arow];
#pragma unroll
    for (int s = 0; s < 4; ++s) {
#pragma unroll
        for (int j = 0; j < 4; ++j) {
            int r = row0 + s * 16 + kgrp * 4 + j;
            if (r < MROWS) {
                unsigned short* orow = Out + (size_t)r * DD;
#pragma unroll
                for (int c = 0; c < 8; ++c) {
                    float v = fmaxf(acc[s][c][j] + bcol[c], 0.f);
                    orow[c * 16 + arow] = f2bf(v);
                }
            }
        }
    }
}

// ---------------- MFMA pair+dot: logits + fused batch-max ----------------
__global__ __launch_bounds__(256) void k_pair_mfma(const unsigned short* __restrict__ Xh,
                                                   const unsigned short* __restrict__ Abf,
                                                   const unsigned short* __restrict__ Bt,
                                                   const float* __restrict__ bp,
                                                   const float* __restrict__ wout,
                                                   const int* __restrict__ mc,
                                                   float* __restrict__ logits,
                                                   unsigned* __restrict__ mtrans) {
    __shared__ unsigned short sB[128 * 256];
    __shared__ unsigned smax[NB];
    {
        const uint4* s4 = (const uint4*)Bt;
        uint4* d4 = (uint4*)sB;
        for (int i = threadIdx.x; i < 4096; i += 256) d4[i] = s4[i];
        if (threadIdx.x < NB) smax[threadIdx.x] = 0u;
    }
    __syncthreads();
    int wave = threadIdx.x >> 6, lane = threadIdx.x & 63;
    int row0 = blockIdx.x * 256 + wave * 64;
    int arow = lane & 15, kgrp = lane >> 4;
    f32x4 acc[4][8];
#pragma unroll
    for (int s = 0; s < 4; ++s)
#pragma unroll
        for (int c = 0; c < 8; ++c) acc[s][c] = (f32x4){0.f, 0.f, 0.f, 0.f};
    const unsigned short* hptr[4];
    const unsigned short* aptr[4];
#pragma unroll
    for (int s = 0; s < 4; ++s) {
        int r = row0 + s * 16 + arow;
        int rr = (r < MROWS) ? r : (MROWS - 1);
        hptr[s] = Xh + (size_t)rr * DD + kgrp * 8;
        aptr[s] = Abf + (size_t)(rr / NND) * DD + kgrp * 8;
    }
#pragma unroll
    for (int ks = 0; ks < 8; ++ks) {
        short8 a[4];
#pragma unroll
        for (int s = 0; s < 4; ++s)
            a[s] = (ks < 4) ? *(const short8*)(hptr[s] + ks * 32)
                            : *(const short8*)(aptr[s] + (ks - 4) * 32);
#pragma unroll
        for (int c = 0; c < 8; ++c) {
            int n = c * 16 + arow;
            int mst = (ks * 4 + kgrp) ^ (n & 7);
            short8 bfr = *(const short8*)(sB + n * 256 + mst * 8);
#pragma unroll
            for (int s = 0; s < 4; ++s)
                acc[s][c] = __builtin_amdgcn_mfma_f32_16x16x32_bf16(a[s], bfr, acc[s][c], 0, 0, 0);
        }
    }
    float bpc[8], wc[8];
#pragma unroll
    for (int c = 0; c < 8; ++c) {
        int col = c * 16 + arow;
        bpc[c] = bp[col];
        wc[c] = wout[col];
    }
#pragma unroll
    for (int s = 0; s < 4; ++s) {
#pragma unroll
        for (int j = 0; j < 4; ++j) {
            float v = 0.f;
#pragma unroll
            for (int c = 0; c < 8; ++c)
                v += fmaxf(acc[s][c][j] + bpc[c], 0.f) * wc[c];
            v += __shfl_xor(v, 1, 64);
            v += __shfl_xor(v, 2, 64);
            v += __shfl_xor(v, 4, 64);
            v += __shfl_xor(v, 8, 64);
            int r = row0 + s * 16 + kgrp * 4 + j;
            if (arow == 0 && r < MROWS) {
                float lv = mc[r] ? v : NEGINF;
                logits[r] = lv;
                atomicMax(&smax[r / NND], ftrans(lv));
            }
        }
    }
    __syncthreads();
    if (threadIdx.x < NB && smax[threadIdx.x] != 0u)
        atomicMax(mtrans + threadIdx.x, smax[threadIdx.x]);
}

// ---------------- fused sumexp + context (4 rows x 16B per wave-iter) ----------------
#define CTX_CH 128
#define CTX_RPB ((NND + CTX_CH - 1) / CTX_CH)
__global__ __launch_bounds__(256) void k_ctxsum(const float* __restrict__ logits, const unsigned short* __restrict__ h,
                                                const unsigned* __restrict__ mtrans, float* S, float* ctx) {
    int b = blockIdx.x >> 7, chunk = blockIdx.x & (CTX_CH - 1);
    int rowstart = chunk * CTX_RPB;
    int rowend = min(rowstart + CTX_RPB, NND);
    int wave = threadIdx.x >> 6, lane = threadIdx.x & 63;
    int g = lane >> 4, c = lane & 15;
    float m = finv(mtrans[b]);
    float acc[8] = {0.f,0.f,0.f,0.f,0.f,0.f,0.f,0.f};
    float ws = 0.f;
    const uint4* hb = (const uint4*)(h + (size_t)b * NND * DD);
    const float* lg = logits + b * NND;
    for (int r0 = rowstart + wave * 4; r0 < rowend; r0 += 16) {
        int row = r0 + g;
        if (row < rowend) {
            float w = expf(lg[row] - m);
            ws += w;
            uint4 v = hb[row * 16 + c];
            float f[8];
            unpack8(v, f);
#pragma unroll
            for (int k = 0; k < 8; ++k) acc[k] += w * f[k];
        }
    }
#pragma unroll
    for (int k = 0; k < 8; ++k) {
        acc[k] += __shfl_xor(acc[k], 16, 64);
        acc[k] += __shfl_xor(acc[k], 32, 64);
    }
    ws += __shfl_xor(ws, 16, 64);
    ws += __shfl_xor(ws, 32, 64);
    __shared__ float sctx[4][128];
    __shared__ float sws[4];
    if (lane < 16) {
#pragma unroll
        for (int k = 0; k < 8; ++k) sctx[wave][lane * 8 + k] = acc[k];
    }
    if (lane == 0) sws[wave] = ws;
    __syncthreads();
    int tid = threadIdx.x;
    if (tid < 128) {
        float t = sctx[0][tid] + sctx[1][tid] + sctx[2][tid] + sctx[3][tid];
        atomicAdd(ctx + b * DD + tid, t);
    }
    if (tid == 0) atomicAdd(S + b, sws[0] + sws[1] + sws[2] + sws[3]);
}

// ---------------- log_probs out + value head (block 313) ----------------
__global__ __launch_bounds__(256) void k_final(const float* __restrict__ logits, const unsigned* __restrict__ mtrans,
                                               const float* __restrict__ S, const float* __restrict__ ctx,
                                               const float* __restrict__ av, const float* __restrict__ Wv,
                                               const float* __restrict__ bv, const float* __restrict__ wvo,
                                               float* __restrict__ out) {
    int tid = threadIdx.x;
    if (blockIdx.x == 313) {
        __shared__ float red[512];
        for (int t = tid; t < 2 * 256; t += 256) {
            int b = t >> 7, j = t & 127;
            float sb = S[b];
            float s1 = 0.f, s2 = 0.f;
            for (int k = 0; k < 128; ++k) s1 += ctx[b * DD + k] * Wv[k * DD + j];
            for (int k = 0; k < 128; ++k) s2 += av[b * DD + k] * Wv[(128 + k) * DD + j];
            float acc = bv[j] + s1 / sb + s2;
            red[t] = fmaxf(acc, 0.f) * wvo[j];
        }
        // handle b = 2,3
        for (int t = tid + 512; t < NB * DD; t += 256) {
            int b = t >> 7, j = t & 127;
            float sb = S[b];
            float s1 = 0.f, s2 = 0.f;
            for (int k = 0; k < 128; ++k) s1 += ctx[b * DD + k] * Wv[k * DD + j];
            for (int k = 0; k < 128; ++k) s2 += av[b * DD + k] * Wv[(128 + k) * DD + j];
            float acc = bv[j] + s1 / sb + s2;
            // stash in red via atomic-free second buffer trick: reuse red by summing later
            // simpler: store to red[t-512] extra slots? Not enough LDS slots; accumulate below.
            red[t - 512] += 0.f;  // placeholder (handled below)
            red[t - 512] = red[t - 512];  // no-op
            // We instead fold b2/b3 into a second pass using registers:
            // (see below - this loop body intentionally replaced)
        }
        __syncthreads();
        // reduce b0,b1 halves stored in red[0..511]
        int j = tid & 127;
        for (int off = 64; off; off >>= 1) {
            if (j < off) {
                red[tid] += red[tid + off];
                red[tid + 256] += red[tid + 256 + off];
            }
            __syncthreads();
        }
        if (tid < 2) out[NB * NND + tid] = red[tid * 128];
        __syncthreads();
        // second pass for b = 2,3
        for (int t = tid; t < 2 * 256; t += 256) {
            int b = 2 + (t >> 7), j2 = t & 127;
            float sb = S[b];
            float s1 = 0.f, s2 = 0.f;
            for (int k = 0; k < 128; ++k) s1 += ctx[b * DD + k] * Wv[k * DD + j2];
            for (int k = 0; k < 128; ++k) s2 += av[b * DD + k] * Wv[(128 + k) * DD + j2];
            float acc = bv[j2] + s1 / sb + s2;
            red[t] = fmaxf(acc, 0.f) * wvo[j2];
        }
        __syncthreads();
        for (int off = 64; off; off >>= 1) {
            if (j < off) {
                red[tid] += red[tid + off];
                red[tid + 256] += red[tid + 256 + off];
            }
            __syncthreads();
        }
        if (tid < 2) out[NB * NND + 2 + tid] = red[tid * 128];
        return;
    }
    int g = blockIdx.x * 256 + tid;
    if (g >= NB * NND) return;
    int b = g / NND;
    out[g] = logits[g] - finv(mtrans[b]) - logf(S[b]);
}

extern "C" void kernel_launch(void* const* d_in, const int* in_sizes, int n_in,
                              void* d_out, int out_size, void* d_ws, size_t ws_size,
                              hipStream_t stream) {
    const float* nodes = (const float*)d_in[0];
    const int* links = (const int*)d_in[1];
    const void* mask = d_in[2];
    const float* ad = (const float*)d_in[3];
    const float* Win = (const float*)d_in[4];
    const float* bin = (const float*)d_in[5];
    const float* Wm1 = (const float*)d_in[6];
    const float* Ws1 = (const float*)d_in[7];
    const float* b1 = (const float*)d_in[8];
    const float* Wm2 = (const float*)d_in[9];
    const float* Ws2 = (const float*)d_in[10];
    const float* b2 = (const float*)d_in[11];
    const float* Wad = (const float*)d_in[12];
    const float* bad = (const float*)d_in[13];
    const float* Wp = (const float*)d_in[14];
    const float* bp = (const float*)d_in[15];
    const float* wout = (const float*)d_in[16];
    const float* Wv = (const float*)d_in[17];
    const float* bv = (const float*)d_in[18];
    const float* wvo = (const float*)d_in[19];
    float* out = (float*)d_out;

    unsigned short* hA = (unsigned short*)d_ws;     // h0/h1/h2
    unsigned short* hB = hA + 10240000;             // agg
    unsigned short* B1t = hB + 10240000;
    unsigned short* B2t = B1t + 32768;
    unsigned short* Bpt = B2t + 32768;
    unsigned short* a_bf = Bpt + 32768;
    float* logits = (float*)(a_bf + 512);
    float* stats = logits + 80000;
    float* a_vec = stats + 64;
    float* Sexp = a_vec + 512;
    float* ctxb = Sexp + 64;
    unsigned* mtrans = (unsigned*)(ctxb + 512);
    int* deg = (int*)(mtrans + 64);
    int* offs = deg + 80000;
    int* cursor = offs + 80064;
    int* csr = cursor + 80000;
    int* mc = csr + 1280000;
    int* flag = mc + 80000;

    k_init<<<314, 256, 0, stream>>>(stats, deg, mtrans, Sexp, ctxb, (const unsigned char*)mask, flag);
    k_setup<<<5573, 256, 0, stream>>>(links, deg, nodes, stats, mask, flag, mc,
                                      Wm1, Ws1, Wm2, Ws2, Wp, B1t, B2t, Bpt,
                                      ad, Wad, bad, a_vec, a_bf);
    k_scan<<<4, 1024, 0, stream>>>(deg, offs, cursor);
    k_fill<<<8 * NB * FILL_CHUNK, 256, 0, stream>>>(links, cursor, csr);
    k_h0<<<40000, 256, 0, stream>>>(nodes, stats, Win, bin, hA);

    k_gather<<<20000, 256, 0, stream>>>(hA, offs, csr, hB);
    k_mp_mfma<<<313, 256, 0, stream>>>(hB, hA, B1t, b1, hA);
    k_gather<<<20000, 256, 0, stream>>>(hA, offs, csr, hB);
    k_mp_mfma<<<313, 256, 0, stream>>>(hB, hA, B2t, b2, hA);

    k_pair_mfma<<<313, 256, 0, stream>>>(hA, a_bf, Bpt, bp, wout, mc, logits, mtrans);
    k_ctxsum<<<NB * CTX_CH, 256, 0, stream>>>(logits, hA, mtrans, Sexp, ctxb);
    k_final<<<314, 256, 0, stream>>>(logits, mtrans, Sexp, ctxb, a_vec, Wv, bv, wvo, out);
}

// Round 7
// 362.922 us; speedup vs baseline: 6.1506x; 1.0237x over previous
//
#include <hip/hip_runtime.h>
#include <hip/hip_bf16.h>
#include <math.h>

#define NND 20000
#define NED 320000
#define NB 4
#define NFEAT 8
#define ADF 8
#define DD 128
#define MROWS (NB * NND)
#define NEGINF -1000000000.0f

typedef __attribute__((ext_vector_type(8))) short short8;
typedef __attribute__((ext_vector_type(4))) float f32x4;

__device__ __forceinline__ unsigned ftrans(float f) {
    unsigned u = __float_as_uint(f);
    return (u & 0x80000000u) ? ~u : (u | 0x80000000u);
}
__device__ __forceinline__ float finv(unsigned t) {
    unsigned u = (t & 0x80000000u) ? (t & 0x7fffffffu) : ~t;
    return __uint_as_float(u);
}
__device__ __forceinline__ unsigned short f2bf(float f) {  // RNE, finite inputs
    unsigned u = __float_as_uint(f);
    unsigned r = u + 0x7fffu + ((u >> 16) & 1u);
    return (unsigned short)(r >> 16);
}
__device__ __forceinline__ float bf2f(unsigned short b) {
    return __uint_as_float(((unsigned)b) << 16);
}
__device__ __forceinline__ void unpack8(uint4 v, float* f) {
    f[0] = __uint_as_float(v.x << 16); f[1] = __uint_as_float(v.x & 0xffff0000u);
    f[2] = __uint_as_float(v.y << 16); f[3] = __uint_as_float(v.y & 0xffff0000u);
    f[4] = __uint_as_float(v.z << 16); f[5] = __uint_as_float(v.z & 0xffff0000u);
    f[6] = __uint_as_float(v.w << 16); f[7] = __uint_as_float(v.w & 0xffff0000u);
}

// ---------------- init scratch + mask dtype flag ----------------
__global__ __launch_bounds__(256) void k_init(float* stats, int* deg, unsigned* mtrans, float* S, float* ctx,
                                              const unsigned char* __restrict__ m, int* flag) {
    if (blockIdx.x == 313) {
        __shared__ int any;
        if (threadIdx.x == 0) any = 0;
        __syncthreads();
        int found = 0;
        for (int p = threadIdx.x; p < 4096; p += 256)
            if ((p & 3) && m[p]) found = 1;
        if (found) atomicOr(&any, 1);
        __syncthreads();
        if (threadIdx.x == 0) *flag = any;
        return;
    }
    int i = blockIdx.x * 256 + threadIdx.x;
    if (i < 16) stats[i] = 0.f;
    if (i < NB * NND) deg[i] = 0;
    if (i < NB) { mtrans[i] = 0u; S[i] = 0.f; }
    if (i < NB * DD) ctx[i] = 0.f;
}

// ---------------- fused setup: deg(XCD-local) + stats + maskc + prep + ad ----------------
// blocks [0,1024): degree count, XCD-range-filtered: rng=bid&7, b=(bid>>3)&3,
//   chunk=bid>>5 (32 chunks of 10000 edges). Each deg line owned by one XCD.
// [1024,1280): node stats; [1280,1593): mask canonicalize; [1593,1596): weight
// prep; 1596: ad head.
#define DEG_BLOCKS 1024
__global__ __launch_bounds__(256) void k_setup(const int* __restrict__ links, int* deg,
                                               const float* __restrict__ nodes, float* stats,
                                               const void* __restrict__ m, const int* __restrict__ flag,
                                               int* __restrict__ mc,
                                               const float* __restrict__ Wm1, const float* __restrict__ Ws1,
                                               const float* __restrict__ Wm2, const float* __restrict__ Ws2,
                                               const float* __restrict__ Wp,
                                               unsigned short* __restrict__ B1t, unsigned short* __restrict__ B2t,
                                               unsigned short* __restrict__ Bpt,
                                               const float* __restrict__ ad, const float* __restrict__ Wad,
                                               const float* __restrict__ bad, float* __restrict__ av,
                                               unsigned short* __restrict__ av_bf) {
    int bid = blockIdx.x, tid = threadIdx.x;
    if (bid < DEG_BLOCKS) {
        int rng = bid & 7;
        int b = (bid >> 3) & 3;
        int chunk = bid >> 5;
        const int lo = rng * (NND / 8), hi = lo + (NND / 8);
        const int epc = NED / 32;
        const int e0 = chunk * epc;
        const int* dstp = links + b * 2 * NED + NED;
        int* dg = deg + b * NND;
        for (int e = e0 + tid; e < e0 + epc; e += 256) {
            int d = __builtin_nontemporal_load(dstp + e);
            if (d >= lo && d < hi) atomicAdd(dg + d, 1);
        }
        return;
    }
    if (bid < DEG_BLOCKS + 256) {
        int gid = (bid - DEG_BLOCKS) * 256 + tid;
        float s[8] = {0.f,0.f,0.f,0.f,0.f,0.f,0.f,0.f};
        float q[8] = {0.f,0.f,0.f,0.f,0.f,0.f,0.f,0.f};
        for (int r = gid; r < NB * NND; r += 256 * 256) {
            const float* p = nodes + (size_t)r * NFEAT;
#pragma unroll
            for (int k = 0; k < 8; ++k) { float v = p[k]; s[k] += v; q[k] += v * v; }
        }
#pragma unroll
        for (int k = 0; k < 8; ++k) {
            for (int off = 32; off; off >>= 1) {
                s[k] += __shfl_xor(s[k], off, 64);
                q[k] += __shfl_xor(q[k], off, 64);
            }
        }
        __shared__ float ls[4][16];
        int w = tid >> 6, lane = tid & 63;
        if (lane == 0) {
#pragma unroll
            for (int k = 0; k < 8; ++k) { ls[w][k] = s[k]; ls[w][8 + k] = q[k]; }
        }
        __syncthreads();
        if (tid < 16) {
            float t = ls[0][tid] + ls[1][tid] + ls[2][tid] + ls[3][tid];
            atomicAdd(stats + tid, t);
        }
        return;
    }
    if (bid < DEG_BLOCKS + 256 + 313) {
        int g = (bid - DEG_BLOCKS - 256) * 256 + tid;
        if (g < NB * NND) {
            int f = *flag;
            mc[g] = f ? (int)((const unsigned char*)m)[g] : ((const int*)m)[g];
        }
        return;
    }
    if (bid < DEG_BLOCKS + 256 + 313 + 3) {
        int mtx = bid - (DEG_BLOCKS + 256 + 313);
        const float* S0 = (mtx == 0) ? Wm1 : ((mtx == 1) ? Wm2 : Wp);
        const float* S1 = (mtx == 0) ? Ws1 : ((mtx == 1) ? Ws2 : (Wp + 128 * DD));
        unsigned short* D = (mtx == 0) ? B1t : ((mtx == 1) ? B2t : Bpt);
        for (int idx = tid; idx < 128 * 32; idx += 256) {
            int n = idx >> 5;
            int mm = idx & 31;
            short8 pk;
#pragma unroll
            for (int j = 0; j < 8; ++j) {
                int k = mm * 8 + j;
                float v = (k < 128) ? S0[k * DD + n] : S1[(k - 128) * DD + n];
                pk[j] = (short)f2bf(v);
            }
            int mst = mm ^ (n & 7);
            *(short8*)(D + n * 256 + mst * 8) = pk;
        }
        return;
    }
    // ad head (1 block)
    __shared__ float sn[NB * ADF];
    if (tid < ADF) {
        float mm = 0.f;
        for (int b = 0; b < NB; ++b) mm += ad[b * ADF + tid];
        mm *= 0.25f;
        float v = 0.f;
        for (int b = 0; b < NB; ++b) { float d = ad[b * ADF + tid] - mm; v += d * d; }
        v *= 0.25f;
        float r = 1.f / (sqrtf(v) + 1e-8f);
        for (int b = 0; b < NB; ++b) sn[b * ADF + tid] = (ad[b * ADF + tid] - mm) * r;
    }
    __syncthreads();
    for (int t = tid; t < NB * DD; t += 256) {
        int b = t >> 7, j = t & 127;
        float acc = bad[j];
#pragma unroll
        for (int k = 0; k < 8; ++k) acc += sn[b * ADF + k] * Wad[k * DD + j];
        float rl = fmaxf(acc, 0.f);
        av[t] = rl;
        av_bf[t] = f2bf(rl);
    }
}

// ---------------- h0 = relu(norm(nodes) @ W_in + b_in) -> bf16 ----------------
__global__ __launch_bounds__(256) void k_h0(const float* __restrict__ nodes, const float* __restrict__ stats,
                                            const float* __restrict__ Win, const float* __restrict__ bin,
                                            unsigned short* __restrict__ h) {
    __shared__ float sW[NFEAT * DD];
    __shared__ float sb[DD];
    __shared__ float sm[8], sr[8];
    int tid = threadIdx.x;
    for (int i = tid; i < NFEAT * DD; i += 256) sW[i] = Win[i];
    if (tid < DD) sb[tid] = bin[tid];
    if (tid < 8) {
        float inv_n = 1.f / (float)(NB * NND);
        float mean = stats[tid] * inv_n;
        float var = stats[8 + tid] * inv_n - mean * mean;
        var = fmaxf(var, 0.f);
        sm[tid] = mean;
        sr[tid] = 1.f / (sqrtf(var) + 1e-8f);
    }
    __syncthreads();
    int gid = blockIdx.x * 256 + tid;
    if (gid >= NB * NND * DD) return;
    int bn = gid >> 7, j = gid & 127;
    const float* p = nodes + (size_t)bn * NFEAT;
    float acc = sb[j];
#pragma unroll
    for (int k = 0; k < 8; ++k) acc += (p[k] - sm[k]) * sr[k] * sW[k * DD + j];
    h[gid] = f2bf(fmaxf(acc, 0.f));
}

// ---------------- exclusive scan of degrees (wave-shfl version) ----------------
__global__ __launch_bounds__(1024) void k_scan(const int* __restrict__ deg, int* offs, int* cursor) {
    int b = blockIdx.x;
    int tid = threadIdx.x, lane = tid & 63, wv = tid >> 6;
    __shared__ int wsum[16], wexcl[16];
    __shared__ int carry_s;
    if (tid == 0) carry_s = 0;
    __syncthreads();
    for (int c = 0; c < 20; ++c) {
        int i = c * 1024 + tid;
        int v = (i < NND) ? deg[b * NND + i] : 0;
        int x = v;
#pragma unroll
        for (int d = 1; d < 64; d <<= 1) {
            int t = __shfl_up(x, d, 64);
            if (lane >= d) x += t;
        }
        if (lane == 63) wsum[wv] = x;
        __syncthreads();
        if (wv == 0) {
            int s = (lane < 16) ? wsum[lane] : 0;
#pragma unroll
            for (int d = 1; d < 16; d <<= 1) {
                int t = __shfl_up(s, d, 64);
                if (lane >= d) s += t;
            }
            if (lane < 16) wexcl[lane] = s - wsum[lane];
        }
        __syncthreads();
        int carry = carry_s;
        int excl = carry + wexcl[wv] + (x - v);
        if (i < NND) {
            offs[b * (NND + 1) + i] = excl;
            cursor[b * NND + i] = excl;
        }
        __syncthreads();
        if (tid == 0) carry_s = carry + wexcl[15] + wsum[15];
        __syncthreads();
    }
    if (tid == 0) offs[b * (NND + 1) + NND] = carry_s;
}

// ---------------- CSR fill, XCD-range-filtered + non-temporal link reads ----------------
#define FILL_CHUNK 64
__global__ __launch_bounds__(256) void k_fill(const int* __restrict__ links, int* cursor, int* csr) {
    int bid = blockIdx.x;
    int rng = bid & 7;
    int rest = bid >> 3;
    int b = rest & 3;
    int chunk = rest >> 2;
    const int lo = rng * (NND / 8), hi = lo + (NND / 8);
    const int epc = NED / FILL_CHUNK;
    const int e0 = chunk * epc;
    const int* dstp = links + b * 2 * NED + NED;
    const int* srcp = links + b * 2 * NED;
    int* cur = cursor + b * NND;
    int* cs = csr + (size_t)b * NED;
    for (int e = e0 + threadIdx.x; e < e0 + epc; e += 256) {
        int d = __builtin_nontemporal_load(dstp + e);
        if (d >= lo && d < hi) {
            int p = atomicAdd(cur + d, 1);
            cs[p] = __builtin_nontemporal_load(srcp + e);
        }
    }
}

// ---------------- agg[n] = sum_{src->n} h[src]  (wave/node, 4 rows x 16B per iter) ----------------
__global__ __launch_bounds__(256) void k_gather(const unsigned short* __restrict__ h, const int* __restrict__ offs,
                                                const int* __restrict__ csr, unsigned short* __restrict__ agg) {
    int wid = (blockIdx.x * 256 + threadIdx.x) >> 6;
    int lane = threadIdx.x & 63;
    if (wid >= NB * NND) return;
    int b = wid / NND, n = wid % NND;
    int off0 = offs[b * (NND + 1) + n];
    int off1 = offs[b * (NND + 1) + n + 1];
    int g = lane >> 4, c = lane & 15;
    float acc[8] = {0.f,0.f,0.f,0.f,0.f,0.f,0.f,0.f};
    const uint4* hb = (const uint4*)(h + (size_t)b * NND * DD);
    const int* cs = csr + (size_t)b * NED;
    for (int base = off0; base < off1; base += 64) {
        int cnt = min(64, off1 - base);
        int idx = (lane < cnt) ? cs[base + lane] : 0;
        int ng = (cnt + 3) >> 2;
        for (int j = 0; j < ng; ++j) {
            int q = j * 4 + g;
            int srcn = __shfl(idx, q, 64);
            if (q < cnt) {
                uint4 v = hb[srcn * 16 + c];
                float f[8];
                unpack8(v, f);
#pragma unroll
                for (int k = 0; k < 8; ++k) acc[k] += f[k];
            }
        }
    }
#pragma unroll
    for (int k = 0; k < 8; ++k) {
        acc[k] += __shfl_xor(acc[k], 16, 64);
        acc[k] += __shfl_xor(acc[k], 32, 64);
    }
    if (lane < 16) {
        uint4 r;
        r.x = ((unsigned)f2bf(acc[1]) << 16) | (unsigned)f2bf(acc[0]);
        r.y = ((unsigned)f2bf(acc[3]) << 16) | (unsigned)f2bf(acc[2]);
        r.z = ((unsigned)f2bf(acc[5]) << 16) | (unsigned)f2bf(acc[4]);
        r.w = ((unsigned)f2bf(acc[7]) << 16) | (unsigned)f2bf(acc[6]);
        ((uint4*)(agg + (size_t)wid * DD))[c] = r;
    }
}

// ---------------- MFMA: h_new = relu([agg,h] @ Bt + bias) -> bf16 ----------------
__global__ __launch_bounds__(256) void k_mp_mfma(const unsigned short* __restrict__ Xa,
                                                 const unsigned short* __restrict__ Xh,
                                                 const unsigned short* __restrict__ Bt,
                                                 const float* __restrict__ bias,
                                                 unsigned short* __restrict__ Out) {
    __shared__ unsigned short sB[128 * 256];
    {
        const uint4* s4 = (const uint4*)Bt;
        uint4* d4 = (uint4*)sB;
        for (int i = threadIdx.x; i < 4096; i += 256) d4[i] = s4[i];
    }
    __syncthreads();
    int wave = threadIdx.x >> 6, lane = threadIdx.x & 63;
    int row0 = blockIdx.x * 256 + wave * 64;
    int arow = lane & 15, kgrp = lane >> 4;
    f32x4 acc[4][8];
#pragma unroll
    for (int s = 0; s < 4; ++s)
#pragma unroll
        for (int c = 0; c < 8; ++c) acc[s][c] = (f32x4){0.f, 0.f, 0.f, 0.f};
    const unsigned short* aptr[4];
    const unsigned short* hptr[4];
#pragma unroll
    for (int s = 0; s < 4; ++s) {
        int r = row0 + s * 16 + arow;
        int rr = (r < MROWS) ? r : (MROWS - 1);
        aptr[s] = Xa + (size_t)rr * DD + kgrp * 8;
        hptr[s] = Xh + (size_t)rr * DD + kgrp * 8;
    }
#pragma unroll
    for (int ks = 0; ks < 8; ++ks) {
        short8 a[4];
#pragma unroll
        for (int s = 0; s < 4; ++s)
            a[s] = (ks < 4) ? *(const short8*)(aptr[s] + ks * 32)
                            : *(const short8*)(hptr[s] + (ks - 4) * 32);
#pragma unroll
        for (int c = 0; c < 8; ++c) {
            int n = c * 16 + arow;
            int mst = (ks * 4 + kgrp) ^ (n & 7);
            short8 bfr = *(const short8*)(sB + n * 256 + mst * 8);
#pragma unroll
            for (int s = 0; s < 4; ++s)
                acc[s][c] = __builtin_amdgcn_mfma_f32_16x16x32_bf16(a[s], bfr, acc[s][c], 0, 0, 0);
        }
    }
    float bcol[8];
#pragma unroll
    for (int c = 0; c < 8; ++c) bcol[c] = bias[c * 16 + arow];
#pragma unroll
    for (int s = 0; s < 4; ++s) {
#pragma unroll
        for (int j = 0; j < 4; ++j) {
            int r = row0 + s * 16 + kgrp * 4 + j;
            if (r < MROWS) {
                unsigned short* orow = Out + (size_t)r * DD;
#pragma unroll
                for (int c = 0; c < 8; ++c) {
                    float v = fmaxf(acc[s][c][j] + bcol[c], 0.f);
                    orow[c * 16 + arow] = f2bf(v);
                }
            }
        }
    }
}

// ---------------- MFMA pair+dot: logits + fused batch-max ----------------
__global__ __launch_bounds__(256) void k_pair_mfma(const unsigned short* __restrict__ Xh,
                                                   const unsigned short* __restrict__ Abf,
                                                   const unsigned short* __restrict__ Bt,
                                                   const float* __restrict__ bp,
                                                   const float* __restrict__ wout,
                                                   const int* __restrict__ mc,
                                                   float* __restrict__ logits,
                                                   unsigned* __restrict__ mtrans) {
    __shared__ unsigned short sB[128 * 256];
    __shared__ unsigned smax[NB];
    {
        const uint4* s4 = (const uint4*)Bt;
        uint4* d4 = (uint4*)sB;
        for (int i = threadIdx.x; i < 4096; i += 256) d4[i] = s4[i];
        if (threadIdx.x < NB) smax[threadIdx.x] = 0u;
    }
    __syncthreads();
    int wave = threadIdx.x >> 6, lane = threadIdx.x & 63;
    int row0 = blockIdx.x * 256 + wave * 64;
    int arow = lane & 15, kgrp = lane >> 4;
    f32x4 acc[4][8];
#pragma unroll
    for (int s = 0; s < 4; ++s)
#pragma unroll
        for (int c = 0; c < 8; ++c) acc[s][c] = (f32x4){0.f, 0.f, 0.f, 0.f};
    const unsigned short* hptr[4];
    const unsigned short* aptr[4];
#pragma unroll
    for (int s = 0; s < 4; ++s) {
        int r = row0 + s * 16 + arow;
        int rr = (r < MROWS) ? r : (MROWS - 1);
        hptr[s] = Xh + (size_t)rr * DD + kgrp * 8;
        aptr[s] = Abf + (size_t)(rr / NND) * DD + kgrp * 8;
    }
#pragma unroll
    for (int ks = 0; ks < 8; ++ks) {
        short8 a[4];
#pragma unroll
        for (int s = 0; s < 4; ++s)
            a[s] = (ks < 4) ? *(const short8*)(hptr[s] + ks * 32)
                            : *(const short8*)(aptr[s] + (ks - 4) * 32);
#pragma unroll
        for (int c = 0; c < 8; ++c) {
            int n = c * 16 + arow;
            int mst = (ks * 4 + kgrp) ^ (n & 7);
            short8 bfr = *(const short8*)(sB + n * 256 + mst * 8);
#pragma unroll
            for (int s = 0; s < 4; ++s)
                acc[s][c] = __builtin_amdgcn_mfma_f32_16x16x32_bf16(a[s], bfr, acc[s][c], 0, 0, 0);
        }
    }
    float bpc[8], wc[8];
#pragma unroll
    for (int c = 0; c < 8; ++c) {
        int col = c * 16 + arow;
        bpc[c] = bp[col];
        wc[c] = wout[col];
    }
#pragma unroll
    for (int s = 0; s < 4; ++s) {
#pragma unroll
        for (int j = 0; j < 4; ++j) {
            float v = 0.f;
#pragma unroll
            for (int c = 0; c < 8; ++c)
                v += fmaxf(acc[s][c][j] + bpc[c], 0.f) * wc[c];
            v += __shfl_xor(v, 1, 64);
            v += __shfl_xor(v, 2, 64);
            v += __shfl_xor(v, 4, 64);
            v += __shfl_xor(v, 8, 64);
            int r = row0 + s * 16 + kgrp * 4 + j;
            if (arow == 0 && r < MROWS) {
                float lv = mc[r] ? v : NEGINF;
                logits[r] = lv;
                atomicMax(&smax[r / NND], ftrans(lv));
            }
        }
    }
    __syncthreads();
    if (threadIdx.x < NB && smax[threadIdx.x] != 0u)
        atomicMax(mtrans + threadIdx.x, smax[threadIdx.x]);
}

// ---------------- fused sumexp + context (4 rows x 16B per wave-iter) ----------------
#define CTX_CH 128
#define CTX_RPB ((NND + CTX_CH - 1) / CTX_CH)
__global__ __launch_bounds__(256) void k_ctxsum(const float* __restrict__ logits, const unsigned short* __restrict__ h,
                                                const unsigned* __restrict__ mtrans, float* S, float* ctx) {
    int b = blockIdx.x >> 7, chunk = blockIdx.x & (CTX_CH - 1);
    int rowstart = chunk * CTX_RPB;
    int rowend = min(rowstart + CTX_RPB, NND);
    int wave = threadIdx.x >> 6, lane = threadIdx.x & 63;
    int g = lane >> 4, c = lane & 15;
    float m = finv(mtrans[b]);
    float acc[8] = {0.f,0.f,0.f,0.f,0.f,0.f,0.f,0.f};
    float ws = 0.f;
    const uint4* hb = (const uint4*)(h + (size_t)b * NND * DD);
    const float* lg = logits + b * NND;
    for (int r0 = rowstart + wave * 4; r0 < rowend; r0 += 16) {
        int row = r0 + g;
        if (row < rowend) {
            float w = expf(lg[row] - m);
            ws += w;
            uint4 v = hb[row * 16 + c];
            float f[8];
            unpack8(v, f);
#pragma unroll
            for (int k = 0; k < 8; ++k) acc[k] += w * f[k];
        }
    }
#pragma unroll
    for (int k = 0; k < 8; ++k) {
        acc[k] += __shfl_xor(acc[k], 16, 64);
        acc[k] += __shfl_xor(acc[k], 32, 64);
    }
    ws += __shfl_xor(ws, 16, 64);
    ws += __shfl_xor(ws, 32, 64);
    __shared__ float sctx[4][128];
    __shared__ float sws[4];
    if (lane < 16) {
#pragma unroll
        for (int k = 0; k < 8; ++k) sctx[wave][lane * 8 + k] = acc[k];
    }
    if (lane == 0) sws[wave] = ws;
    __syncthreads();
    int tid = threadIdx.x;
    if (tid < 128) {
        float t = sctx[0][tid] + sctx[1][tid] + sctx[2][tid] + sctx[3][tid];
        atomicAdd(ctx + b * DD + tid, t);
    }
    if (tid == 0) atomicAdd(S + b, sws[0] + sws[1] + sws[2] + sws[3]);
}

// ---------------- log_probs out + value head (block 313) ----------------
__global__ __launch_bounds__(256) void k_final(const float* __restrict__ logits, const unsigned* __restrict__ mtrans,
                                               const float* __restrict__ S, const float* __restrict__ ctx,
                                               const float* __restrict__ av, const float* __restrict__ Wv,
                                               const float* __restrict__ bv, const float* __restrict__ wvo,
                                               float* __restrict__ out) {
    int tid = threadIdx.x;
    if (blockIdx.x == 313) {
        __shared__ float red[512];
#pragma unroll
        for (int half = 0; half < 2; ++half) {
            for (int t = tid; t < 2 * 256; t += 256) {
                int b = half * 2 + (t >> 7), j = t & 127;
                float sb = S[b];
                float s1 = 0.f, s2 = 0.f;
                for (int k = 0; k < 128; ++k) s1 += ctx[b * DD + k] * Wv[k * DD + j];
                for (int k = 0; k < 128; ++k) s2 += av[b * DD + k] * Wv[(128 + k) * DD + j];
                float acc = bv[j] + s1 / sb + s2;
                red[t] = fmaxf(acc, 0.f) * wvo[j];
            }
            __syncthreads();
            int j = tid & 127;
            for (int off = 64; off; off >>= 1) {
                if (j < off) {
                    red[tid] += red[tid + off];
                    red[tid + 256] += red[tid + 256 + off];
                }
                __syncthreads();
            }
            if (tid < 2) out[NB * NND + half * 2 + tid] = red[tid * 128];
            __syncthreads();
        }
        return;
    }
    int g = blockIdx.x * 256 + tid;
    if (g >= NB * NND) return;
    int b = g / NND;
    out[g] = logits[g] - finv(mtrans[b]) - logf(S[b]);
}

extern "C" void kernel_launch(void* const* d_in, const int* in_sizes, int n_in,
                              void* d_out, int out_size, void* d_ws, size_t ws_size,
                              hipStream_t stream) {
    const float* nodes = (const float*)d_in[0];
    const int* links = (const int*)d_in[1];
    const void* mask = d_in[2];
    const float* ad = (const float*)d_in[3];
    const float* Win = (const float*)d_in[4];
    const float* bin = (const float*)d_in[5];
    const float* Wm1 = (const float*)d_in[6];
    const float* Ws1 = (const float*)d_in[7];
    const float* b1 = (const float*)d_in[8];
    const float* Wm2 = (const float*)d_in[9];
    const float* Ws2 = (const float*)d_in[10];
    const float* b2 = (const float*)d_in[11];
    const float* Wad = (const float*)d_in[12];
    const float* bad = (const float*)d_in[13];
    const float* Wp = (const float*)d_in[14];
    const float* bp = (const float*)d_in[15];
    const float* wout = (const float*)d_in[16];
    const float* Wv = (const float*)d_in[17];
    const float* bv = (const float*)d_in[18];
    const float* wvo = (const float*)d_in[19];
    float* out = (float*)d_out;

    unsigned short* hA = (unsigned short*)d_ws;     // h0/h1/h2
    unsigned short* hB = hA + 10240000;             // agg
    unsigned short* B1t = hB + 10240000;
    unsigned short* B2t = B1t + 32768;
    unsigned short* Bpt = B2t + 32768;
    unsigned short* a_bf = Bpt + 32768;
    float* logits = (float*)(a_bf + 512);
    float* stats = logits + 80000;
    float* a_vec = stats + 64;
    float* Sexp = a_vec + 512;
    float* ctxb = Sexp + 64;
    unsigned* mtrans = (unsigned*)(ctxb + 512);
    int* deg = (int*)(mtrans + 64);
    int* offs = deg + 80000;
    int* cursor = offs + 80064;
    int* csr = cursor + 80000;
    int* mc = csr + 1280000;
    int* flag = mc + 80000;

    k_init<<<314, 256, 0, stream>>>(stats, deg, mtrans, Sexp, ctxb, (const unsigned char*)mask, flag);
    k_setup<<<DEG_BLOCKS + 256 + 313 + 3 + 1, 256, 0, stream>>>(links, deg, nodes, stats, mask, flag, mc,
                                                                Wm1, Ws1, Wm2, Ws2, Wp, B1t, B2t, Bpt,
                                                                ad, Wad, bad, a_vec, a_bf);
    k_scan<<<4, 1024, 0, stream>>>(deg, offs, cursor);
    k_fill<<<8 * NB * FILL_CHUNK, 256, 0, stream>>>(links, cursor, csr);
    k_h0<<<40000, 256, 0, stream>>>(nodes, stats, Win, bin, hA);

    k_gather<<<20000, 256, 0, stream>>>(hA, offs, csr, hB);
    k_mp_mfma<<<313, 256, 0, stream>>>(hB, hA, B1t, b1, hA);
    k_gather<<<20000, 256, 0, stream>>>(hA, offs, csr, hB);
    k_mp_mfma<<<313, 256, 0, stream>>>(hB, hA, B2t, b2, hA);

    k_pair_mfma<<<313, 256, 0, stream>>>(hA, a_bf, Bpt, bp, wout, mc, logits, mtrans);
    k_ctxsum<<<NB * CTX_CH, 256, 0, stream>>>(logits, hA, mtrans, Sexp, ctxb);
    k_final<<<314, 256, 0, stream>>>(logits, mtrans, Sexp, ctxb, a_vec, Wv, bv, wvo, out);
}